// Round 1
// baseline (3353.749 us; speedup 1.0000x reference)
//
#include <hip/hip_runtime.h>
#include <math.h>

// ---------------- problem constants ----------------
#define BB_   16
#define TT_   1000     // T after removing padding
#define TTOT_ 1100
#define NPAD_ 100
#define DD_   256      // model dim
#define NN_   256      // neurons
#define FF_   1024
#define NH_   8
#define HD_   32

// workspace layout (in floats)
#define X_OFF    0u
#define O_OFF    4096000u
#define BIG_OFF  8192000u
#define PP_OFF   24576000u          // pool partials 16*8*256
#define PL_OFF   (PP_OFF + 32768u)  // pooled 16*256
#define CF_OFF   (PL_OFF + 4096u)   // coeffs 16*120
#define CB_OFF   (CF_OFF + 1920u)   // combined conv kernel 256*20

// ---------------- tiled fp32 GEMM: C = act(A@B + bias [+ resid]) ----------------
// A: MxK row-major, B: KxN row-major. M%64==0, N%64==0, K%16==0.
// ACT: 0=none, 1=gelu(exact)
template<int ACT>
__global__ __launch_bounds__(256) void gemm_k(const float* __restrict__ A,
                                              const float* __restrict__ Bm,
                                              const float* __restrict__ bias,
                                              const float* __restrict__ resid,
                                              float* __restrict__ C,
                                              int M, int N, int K)
{
    __shared__ float As[16][68];
    __shared__ float Bs[16][68];
    const int tid = threadIdx.x;
    const int m0 = blockIdx.x * 64, n0 = blockIdx.y * 64;
    const int ty = tid >> 4, tx = tid & 15;
    const int la_m = tid >> 2, la_k = (tid & 3) * 4;
    const int lb_k = tid >> 4, lb_n = (tid & 15) * 4;

    float acc[4][4] = {};
    for (int k0 = 0; k0 < K; k0 += 16) {
        float4 a4 = *(const float4*)(A + (size_t)(m0 + la_m) * K + k0 + la_k);
        float4 b4 = *(const float4*)(Bm + (size_t)(k0 + lb_k) * N + n0 + lb_n);
        __syncthreads();
        As[la_k + 0][la_m] = a4.x; As[la_k + 1][la_m] = a4.y;
        As[la_k + 2][la_m] = a4.z; As[la_k + 3][la_m] = a4.w;
        Bs[lb_k][lb_n + 0] = b4.x; Bs[lb_k][lb_n + 1] = b4.y;
        Bs[lb_k][lb_n + 2] = b4.z; Bs[lb_k][lb_n + 3] = b4.w;
        __syncthreads();
        #pragma unroll
        for (int k = 0; k < 16; ++k) {
            float ar[4], br[4];
            #pragma unroll
            for (int i = 0; i < 4; ++i) ar[i] = As[k][ty * 4 + i];
            #pragma unroll
            for (int j = 0; j < 4; ++j) br[j] = Bs[k][tx * 4 + j];
            #pragma unroll
            for (int i = 0; i < 4; ++i)
                #pragma unroll
                for (int j = 0; j < 4; ++j) acc[i][j] += ar[i] * br[j];
        }
    }
    #pragma unroll
    for (int i = 0; i < 4; ++i) {
        const int row = m0 + ty * 4 + i;
        #pragma unroll
        for (int j = 0; j < 4; ++j) {
            const int col = n0 + tx * 4 + j;
            float v = acc[i][j] + bias[col];
            if (resid) v += resid[(size_t)row * N + col];
            if (ACT == 1) v = 0.5f * v * (1.0f + erff(v * 0.70710678118654752f));
            C[(size_t)row * N + col] = v;
        }
    }
}

// ---------------- token embedding + positional encoding ----------------
// X[b,t,d] = sum_n Y[b,n,NPAD+t]*token_W[n,d] + token_b[d] + pe(t,d)
__global__ __launch_bounds__(256) void embed_k(const float* __restrict__ Y,
                                               const float* __restrict__ W,
                                               const float* __restrict__ bias,
                                               float* __restrict__ X)
{
    __shared__ float As[16][68];
    __shared__ float Bs[16][68];
    const int tid = threadIdx.x;
    const int m0 = blockIdx.x * 64, n0 = blockIdx.y * 64;
    const int ty = tid >> 4, tx = tid & 15;
    const int la_m = tid >> 2, la_k = (tid & 3) * 4;
    const int lb_k = tid >> 4, lb_n = (tid & 15) * 4;

    const int rowA = m0 + la_m;
    const int bb = rowA / TT_, tt = rowA - bb * TT_;
    const float* yb = Y + (size_t)bb * NN_ * TTOT_ + NPAD_ + tt;

    float acc[4][4] = {};
    for (int k0 = 0; k0 < NN_; k0 += 16) {
        float a[4];
        #pragma unroll
        for (int j = 0; j < 4; ++j) a[j] = yb[(size_t)(k0 + la_k + j) * TTOT_];
        float4 b4 = *(const float4*)(W + (size_t)(k0 + lb_k) * DD_ + n0 + lb_n);
        __syncthreads();
        As[la_k + 0][la_m] = a[0]; As[la_k + 1][la_m] = a[1];
        As[la_k + 2][la_m] = a[2]; As[la_k + 3][la_m] = a[3];
        Bs[lb_k][lb_n + 0] = b4.x; Bs[lb_k][lb_n + 1] = b4.y;
        Bs[lb_k][lb_n + 2] = b4.z; Bs[lb_k][lb_n + 3] = b4.w;
        __syncthreads();
        #pragma unroll
        for (int k = 0; k < 16; ++k) {
            float ar[4], br[4];
            #pragma unroll
            for (int i = 0; i < 4; ++i) ar[i] = As[k][ty * 4 + i];
            #pragma unroll
            for (int j = 0; j < 4; ++j) br[j] = Bs[k][tx * 4 + j];
            #pragma unroll
            for (int i = 0; i < 4; ++i)
                #pragma unroll
                for (int j = 0; j < 4; ++j) acc[i][j] += ar[i] * br[j];
        }
    }
    #pragma unroll
    for (int i = 0; i < 4; ++i) {
        const int row = m0 + ty * 4 + i;
        const int t = row % TT_;
        #pragma unroll
        for (int j = 0; j < 4; ++j) {
            const int col = n0 + tx * 4 + j;
            float v = acc[i][j] + bias[col];
            const int i2 = col >> 1;
            const float div = expf(-(float)(2 * i2) * 0.0269834190585241f); // ln(1000)/256
            const float ang = (float)t * div;
            v += (col & 1) ? cosf(ang) : sinf(ang);
            X[(size_t)row * DD_ + col] = v;
        }
    }
}

// ---------------- flash attention (fp32) ----------------
// qkv: (B*T, 768) rows = [q(256) | k(256) | v(256)], heads of 32.
// o:   (B*T, 256)
__global__ __launch_bounds__(256) void attn_k(const float* __restrict__ qkv,
                                              float* __restrict__ o)
{
    const int qt = blockIdx.x, h = blockIdx.y, b = blockIdx.z;
    const int tid = threadIdx.x, ty = tid >> 4, tx = tid & 15;
    __shared__ float Qs[64][33], Ks[64][33], Vs[64][33], Ps[64][65];

    for (int idx = tid; idx < 512; idx += 256) {
        const int row = idx >> 3, c4 = (idx & 7) * 4;
        const int t = qt * 64 + row;
        float4 q4 = make_float4(0.f, 0.f, 0.f, 0.f);
        if (t < TT_) q4 = *(const float4*)(qkv + ((size_t)(b * TT_ + t)) * 768 + h * 32 + c4);
        Qs[row][c4] = q4.x; Qs[row][c4 + 1] = q4.y; Qs[row][c4 + 2] = q4.z; Qs[row][c4 + 3] = q4.w;
    }

    float m[4], l[4], accO[4][2];
    #pragma unroll
    for (int i = 0; i < 4; ++i) { m[i] = -1e30f; l[i] = 0.f; accO[i][0] = 0.f; accO[i][1] = 0.f; }

    const float sc = 0.17677669529663687f; // 1/sqrt(32)
    for (int kt = 0; kt < 16; ++kt) {
        __syncthreads();
        for (int idx = tid; idx < 512; idx += 256) {
            const int row = idx >> 3, c4 = (idx & 7) * 4;
            const int t = kt * 64 + row;
            float4 k4 = make_float4(0.f, 0.f, 0.f, 0.f);
            float4 v4 = make_float4(0.f, 0.f, 0.f, 0.f);
            if (t < TT_) {
                const size_t base = ((size_t)(b * TT_ + t)) * 768 + h * 32;
                k4 = *(const float4*)(qkv + base + 256 + c4);
                v4 = *(const float4*)(qkv + base + 512 + c4);
            }
            Ks[row][c4] = k4.x; Ks[row][c4 + 1] = k4.y; Ks[row][c4 + 2] = k4.z; Ks[row][c4 + 3] = k4.w;
            Vs[row][c4] = v4.x; Vs[row][c4 + 1] = v4.y; Vs[row][c4 + 2] = v4.z; Vs[row][c4 + 3] = v4.w;
        }
        __syncthreads();

        float s[4][4] = {};
        #pragma unroll 8
        for (int d = 0; d < 32; ++d) {
            float ar[4], br[4];
            #pragma unroll
            for (int i = 0; i < 4; ++i) ar[i] = Qs[ty * 4 + i][d];
            #pragma unroll
            for (int j = 0; j < 4; ++j) br[j] = Ks[tx * 4 + j][d];
            #pragma unroll
            for (int i = 0; i < 4; ++i)
                #pragma unroll
                for (int j = 0; j < 4; ++j) s[i][j] += ar[i] * br[j];
        }

        float p[4][4];
        #pragma unroll
        for (int i = 0; i < 4; ++i) {
            float mm = -1e30f;
            #pragma unroll
            for (int j = 0; j < 4; ++j) {
                const int kc = kt * 64 + tx * 4 + j;
                s[i][j] = (kc < TT_) ? s[i][j] * sc : -1e30f;
                mm = fmaxf(mm, s[i][j]);
            }
            #pragma unroll
            for (int msk = 1; msk < 16; msk <<= 1) mm = fmaxf(mm, __shfl_xor(mm, msk));
            const float mn = fmaxf(m[i], mm);
            const float alpha = expf(m[i] - mn);
            float ss = 0.f;
            #pragma unroll
            for (int j = 0; j < 4; ++j) { p[i][j] = expf(s[i][j] - mn); ss += p[i][j]; }
            #pragma unroll
            for (int msk = 1; msk < 16; msk <<= 1) ss += __shfl_xor(ss, msk);
            l[i] = l[i] * alpha + ss;
            m[i] = mn;
            accO[i][0] *= alpha; accO[i][1] *= alpha;
        }
        #pragma unroll
        for (int i = 0; i < 4; ++i)
            #pragma unroll
            for (int j = 0; j < 4; ++j) Ps[ty * 4 + i][tx * 4 + j] = p[i][j];
        __syncthreads();

        #pragma unroll 8
        for (int jj = 0; jj < 64; ++jj) {
            const float v0 = Vs[jj][tx * 2], v1 = Vs[jj][tx * 2 + 1];
            #pragma unroll
            for (int i = 0; i < 4; ++i) {
                const float pp = Ps[ty * 4 + i][jj];
                accO[i][0] += pp * v0; accO[i][1] += pp * v1;
            }
        }
    }

    #pragma unroll
    for (int i = 0; i < 4; ++i) {
        const int t = qt * 64 + ty * 4 + i;
        if (t < TT_) {
            const float inv = 1.f / l[i];
            const size_t base = ((size_t)(b * TT_ + t)) * 256 + h * 32 + tx * 2;
            o[base] = accO[i][0] * inv;
            o[base + 1] = accO[i][1] * inv;
        }
    }
}

// ---------------- LayerNorm over last dim (256) ----------------
__global__ __launch_bounds__(256) void ln_k(const float* __restrict__ in,
                                            const float* __restrict__ g,
                                            const float* __restrict__ b,
                                            float* __restrict__ out)
{
    const int row = blockIdx.x, d = threadIdx.x;
    const size_t base = (size_t)row * 256;
    const float v = in[base + d];
    float s = v;
    #pragma unroll
    for (int msk = 32; msk; msk >>= 1) s += __shfl_xor(s, msk);
    __shared__ float r1[4], r2[4];
    const int w = d >> 6;
    if ((d & 63) == 0) r1[w] = s;
    __syncthreads();
    const float mean = (r1[0] + r1[1] + r1[2] + r1[3]) * (1.f / 256.f);
    const float dv = v - mean;
    float q = dv * dv;
    #pragma unroll
    for (int msk = 32; msk; msk >>= 1) q += __shfl_xor(q, msk);
    if ((d & 63) == 0) r2[w] = q;
    __syncthreads();
    const float var = (r2[0] + r2[1] + r2[2] + r2[3]) * (1.f / 256.f);
    out[base + d] = dv * rsqrtf(var + 1e-5f) * g[d] + b[d];
}

// ---------------- mean pool over T ----------------
__global__ __launch_bounds__(256) void pool_part_k(const float* __restrict__ X,
                                                   float* __restrict__ partial)
{
    const int b = blockIdx.x, seg = blockIdx.y, d = threadIdx.x;
    float s = 0.f;
    const int t0 = seg * 125;
    for (int t = t0; t < t0 + 125; ++t) s += X[((size_t)b * TT_ + t) * 256 + d];
    partial[(b * 8 + seg) * 256 + d] = s;
}
__global__ __launch_bounds__(256) void pool_red_k(const float* __restrict__ partial,
                                                  float* __restrict__ pooled)
{
    const int b = blockIdx.x, d = threadIdx.x;
    float s = 0.f;
    for (int k = 0; k < 8; ++k) s += partial[(b * 8 + k) * 256 + d];
    pooled[b * 256 + d] = s * (1.f / (float)TT_);
}

// ---------------- decode head: pooled -> coeffs(16,120) ----------------
__global__ __launch_bounds__(128) void head_k(const float* __restrict__ pooled,
                                              const float* __restrict__ toLW,
                                              const float* __restrict__ toLb,
                                              const float* __restrict__ dW1,
                                              const float* __restrict__ db1,
                                              const float* __restrict__ dW2,
                                              const float* __restrict__ db2,
                                              float* __restrict__ coeffs)
{
    const int b = blockIdx.x, j = threadIdx.x;
    __shared__ float hs[64];
    __shared__ float hid[128];
    float a = toLb[j];
    for (int d = 0; d < 256; ++d) a += pooled[b * 256 + d] * toLW[d * 128 + j];
    if (j < 64) hs[j] = a;
    __syncthreads();
    float a2 = db1[j];
    for (int z = 0; z < 64; ++z) a2 += hs[z] * dW1[z * 128 + j];
    hid[j] = fmaxf(a2, 0.f);
    __syncthreads();
    if (j < 120) {
        float a3 = db2[j];
        for (int k = 0; k < 128; ++k) a3 += hid[k] * dW2[k * 120 + j];
        coeffs[b * 120 + j] = a3;
    }
}

// ---------------- combined conv kernel per neuron: comb[n][tau] ----------------
__global__ void comb_k(const float* __restrict__ selfK,
                       const float* __restrict__ cplW,
                       const float* __restrict__ cplB,
                       float* __restrict__ comb)
{
    const int n = threadIdx.x;
    for (int ti = 0; ti < 20; ++ti) {
        float s = selfK[ti * 256 + n];
        #pragma unroll
        for (int si = 0; si < 4; ++si) s += cplW[n * 4 + si] * cplB[ti * 4 + si];
        comb[n * 20 + ti] = s;
    }
}

// ---------------- final: sti + cpl + slf ----------------
__global__ __launch_bounds__(256) void final_k(const float* __restrict__ Y,
                                               const float* __restrict__ SB,
                                               const float* __restrict__ roW,
                                               const float* __restrict__ coeffs,
                                               const float* __restrict__ comb,
                                               float* __restrict__ out)
{
    const int bx = blockIdx.x;
    const int b = bx >> 8, n = bx & 255;
    const int tid = threadIdx.x;
    __shared__ float w[30], ck[20];
    if (tid < 30) {
        float s = 0.f;
        #pragma unroll
        for (int f = 0; f < 4; ++f) s += roW[n * 4 + f] * coeffs[b * 120 + f * 30 + tid];
        w[tid] = s;
    }
    if (tid < 20) ck[tid] = comb[n * 20 + tid];
    __syncthreads();
    const float* yb = Y + ((size_t)b * 256 + n) * TTOT_;
    float* ob = out + ((size_t)b * 256 + n) * TT_;
    for (int t = tid; t < TT_; t += 256) {
        float acc = 0.f;
        const float* sb = SB + (size_t)t * 30;
        #pragma unroll
        for (int k = 0; k < 30; ++k) acc += w[k] * sb[k];
        #pragma unroll
        for (int tau = 1; tau <= 20; ++tau) acc += ck[tau - 1] * yb[t + NPAD_ - tau];
        ob[t] = acc;
    }
}

// ---------------- launch ----------------
extern "C" void kernel_launch(void* const* d_in, const int* in_sizes, int n_in,
                              void* d_out, int out_size, void* d_ws, size_t ws_size,
                              hipStream_t stream)
{
    const float* Y      = (const float*)d_in[0];
    const float* tokW   = (const float*)d_in[1];
    const float* tokb   = (const float*)d_in[2];
    const float* Wqkv   = (const float*)d_in[3];
    const float* bqkv   = (const float*)d_in[4];
    const float* Wo     = (const float*)d_in[5];
    const float* bo     = (const float*)d_in[6];
    const float* ln1g   = (const float*)d_in[7];
    const float* ln1b   = (const float*)d_in[8];
    const float* W1     = (const float*)d_in[9];
    const float* b1     = (const float*)d_in[10];
    const float* W2     = (const float*)d_in[11];
    const float* b2     = (const float*)d_in[12];
    const float* ln2g   = (const float*)d_in[13];
    const float* ln2b   = (const float*)d_in[14];
    const float* toLW   = (const float*)d_in[15];
    const float* toLb   = (const float*)d_in[16];
    const float* dW1    = (const float*)d_in[17];
    const float* db1    = (const float*)d_in[18];
    const float* dW2    = (const float*)d_in[19];
    const float* db2    = (const float*)d_in[20];
    const float* SB     = (const float*)d_in[21];
    const float* roW    = (const float*)d_in[22];
    const float* cplW   = (const float*)d_in[23];
    const float* cplB   = (const float*)d_in[24];
    const float* selfK  = (const float*)d_in[25];

    float* ws  = (float*)d_ws;
    float* X   = ws + X_OFF;
    float* O   = ws + O_OFF;
    float* BIG = ws + BIG_OFF;
    float* PP  = ws + PP_OFF;
    float* PL  = ws + PL_OFF;
    float* CF  = ws + CF_OFF;
    float* CB  = ws + CB_OFF;

    embed_k<<<dim3(250, 4), 256, 0, stream>>>(Y, tokW, tokb, X);

    for (int l = 0; l < 4; ++l) {
        gemm_k<0><<<dim3(250, 12), 256, 0, stream>>>(X, Wqkv + (size_t)l * 256 * 768,
                                                     bqkv + l * 768, nullptr, BIG,
                                                     16000, 768, 256);
        attn_k<<<dim3(16, 8, 16), 256, 0, stream>>>(BIG, O);
        gemm_k<0><<<dim3(250, 4), 256, 0, stream>>>(O, Wo + (size_t)l * 256 * 256,
                                                    bo + l * 256, X, BIG,
                                                    16000, 256, 256);
        ln_k<<<16000, 256, 0, stream>>>(BIG, ln1g + l * 256, ln1b + l * 256, X);
        gemm_k<1><<<dim3(250, 16), 256, 0, stream>>>(X, W1 + (size_t)l * 256 * 1024,
                                                     b1 + l * 1024, nullptr, BIG,
                                                     16000, 1024, 256);
        gemm_k<0><<<dim3(250, 4), 256, 0, stream>>>(BIG, W2 + (size_t)l * 1024 * 256,
                                                    b2 + l * 256, X, O,
                                                    16000, 256, 1024);
        ln_k<<<16000, 256, 0, stream>>>(O, ln2g + l * 256, ln2b + l * 256, X);
    }

    pool_part_k<<<dim3(16, 8), 256, 0, stream>>>(X, PP);
    pool_red_k<<<16, 256, 0, stream>>>(PP, PL);
    head_k<<<16, 128, 0, stream>>>(PL, toLW, toLb, dW1, db1, dW2, db2, CF);
    comb_k<<<1, 256, 0, stream>>>(selfK, cplW, cplB, CB);
    final_k<<<4096, 256, 0, stream>>>(Y, SB, roW, CF, CB, (float*)d_out);
}

// Round 2
// 1090.066 us; speedup vs baseline: 3.0766x; 3.0766x over previous
//
#include <hip/hip_runtime.h>
#include <math.h>

// ---------------- problem constants ----------------
#define TT_   1000
#define TTOT_ 1100
#define NPAD_ 100
#define DD_   256
#define NN_   256

// workspace layout (float units)
#define X_OFF    0u           // fp32 residual stream 16000x256
#define XB_OFF   4096000u     // bf16 copy of X
#define O_OFF    6144000u     // bf16 attn out 16000x256
#define R_OFF    8192000u     // fp32 pre-LN buffer 16000x256
#define BIG_OFF  12288000u    // bf16 16000x1024 max (qkv 16000x768 / ff 16000x1024)
#define WT_OFF   20480000u    // bf16 transposed weights (3,145,728 shorts)
#define PP_OFF   22052864u
#define PL_OFF   (PP_OFF + 32768u)
#define CF_OFF   (PL_OFF + 4096u)
#define CB_OFF   (CF_OFF + 1920u)

typedef __attribute__((ext_vector_type(8))) short s16x8;
typedef __attribute__((ext_vector_type(4))) float f32x4;

__device__ inline short f2bf(float f) {
    unsigned u = __float_as_uint(f);
    u += 0x7fffu + ((u >> 16) & 1u);
    return (short)(u >> 16);
}

// ---------------- weight transpose-convert: in KxN fp32 -> out NxK bf16, batched L ----------------
__global__ __launch_bounds__(256) void wtr_k(const float* __restrict__ in,
                                             short* __restrict__ out, int K, int N)
{
    __shared__ float t[32][33];
    const int n0 = blockIdx.x * 32, k0 = blockIdx.y * 32;
    in  += (size_t)blockIdx.z * K * N;
    out += (size_t)blockIdx.z * K * N;
    const int tx = threadIdx.x & 31, ty = threadIdx.x >> 5;
    #pragma unroll
    for (int i = 0; i < 4; ++i)
        t[ty + 8 * i][tx] = in[(size_t)(k0 + ty + 8 * i) * N + n0 + tx];
    __syncthreads();
    #pragma unroll
    for (int i = 0; i < 4; ++i)
        out[(size_t)(n0 + ty + 8 * i) * K + k0 + tx] = f2bf(t[tx][ty + 8 * i]);
}

// ---------------- bf16 MFMA GEMM: C = act(A@Bt^T + bias [+resid]) ----------------
// A: MxK bf16 row-major. Bt: NxK bf16 row-major. 128x128 tile, 4 waves (2x2), BK=64.
// M%128==0, N%128==0, K%64==0.
template<int OUTBF, int ACT, int RES>
__global__ __launch_bounds__(256) void bgemm_k(const short* __restrict__ A,
                                               const short* __restrict__ Bt,
                                               const float* __restrict__ bias,
                                               const float* __restrict__ resid,
                                               void* __restrict__ Cout,
                                               int M, int N, int K)
{
    __shared__ short As[128 * 64];
    __shared__ short Bs[128 * 64];
    const int tid = threadIdx.x;
    const int m0 = blockIdx.x * 128, n0 = blockIdx.y * 128;
    const int wv = tid >> 6, lane = tid & 63;
    const int wr = wv >> 1, wc = wv & 1;
    const int l15 = lane & 15, lg = lane >> 4;

    f32x4 acc[4][4];
    #pragma unroll
    for (int i = 0; i < 4; ++i)
        #pragma unroll
        for (int j = 0; j < 4; ++j) acc[i][j] = (f32x4){0.f, 0.f, 0.f, 0.f};

    for (int k0 = 0; k0 < K; k0 += 64) {
        __syncthreads();
        #pragma unroll
        for (int i = 0; i < 4; ++i) {
            const int cid = tid + i * 256;
            const int r = cid >> 3, c = cid & 7;
            s16x8 av = *(const s16x8*)(A + (size_t)(m0 + r) * K + k0 + c * 8);
            *(s16x8*)(As + r * 64 + ((c ^ (r & 7)) * 8)) = av;
            s16x8 bv = *(const s16x8*)(Bt + (size_t)(n0 + r) * K + k0 + c * 8);
            *(s16x8*)(Bs + r * 64 + ((c ^ (r & 7)) * 8)) = bv;
        }
        __syncthreads();
        #pragma unroll
        for (int ks = 0; ks < 2; ++ks) {
            s16x8 af[4], bf[4];
            #pragma unroll
            for (int mi = 0; mi < 4; ++mi) {
                const int row = wr * 64 + mi * 16 + l15;
                const int ch = ks * 4 + lg;
                af[mi] = *(const s16x8*)(As + row * 64 + ((ch ^ (row & 7)) * 8));
            }
            #pragma unroll
            for (int ni = 0; ni < 4; ++ni) {
                const int col = wc * 64 + ni * 16 + l15;
                const int ch = ks * 4 + lg;
                bf[ni] = *(const s16x8*)(Bs + col * 64 + ((ch ^ (col & 7)) * 8));
            }
            #pragma unroll
            for (int mi = 0; mi < 4; ++mi)
                #pragma unroll
                for (int ni = 0; ni < 4; ++ni)
                    acc[mi][ni] = __builtin_amdgcn_mfma_f32_16x16x32_bf16(
                        af[mi], bf[ni], acc[mi][ni], 0, 0, 0);
        }
    }

    #pragma unroll
    for (int mi = 0; mi < 4; ++mi) {
        #pragma unroll
        for (int ni = 0; ni < 4; ++ni) {
            const int col = n0 + wc * 64 + ni * 16 + l15;
            const float bv = bias[col];
            #pragma unroll
            for (int r = 0; r < 4; ++r) {
                const int row = m0 + wr * 64 + mi * 16 + lg * 4 + r;
                float v = acc[mi][ni][r] + bv;
                if (RES) v += resid[(size_t)row * N + col];
                if (ACT) v = 0.5f * v * (1.0f + erff(v * 0.70710678118654752f));
                if (OUTBF) ((short*)Cout)[(size_t)row * N + col] = f2bf(v);
                else       ((float*)Cout)[(size_t)row * N + col] = v;
            }
        }
    }
}

// ---------------- MFMA flash attention (bf16) ----------------
// qkv: (16*1000) x 768 bf16 rows [q|k|v], heads of 32. o: (16*1000) x 256 bf16.
__global__ __launch_bounds__(256) void mattn_k(const short* __restrict__ qkv,
                                               short* __restrict__ o)
{
    const int qt = blockIdx.x, h = blockIdx.y, b = blockIdx.z;
    const int tid = threadIdx.x, wv = tid >> 6, lane = tid & 63;
    const int l15 = lane & 15, lg = lane >> 4;
    __shared__ short Ks[64 * 40];
    __shared__ short Vt[32 * 72];
    __shared__ short Ps[4][32 * 64];

    const int q0 = qt * 128 + wv * 32;
    s16x8 aq[2];
    #pragma unroll
    for (int mi = 0; mi < 2; ++mi) {
        int t = q0 + mi * 16 + l15; if (t > 999) t = 999;
        aq[mi] = *(const s16x8*)(qkv + ((size_t)(b * TT_ + t)) * 768 + h * 32 + lg * 8);
    }

    float mst[2][4], lst[2][4];
    f32x4 oacc[2][2];
    #pragma unroll
    for (int mi = 0; mi < 2; ++mi) {
        #pragma unroll
        for (int r = 0; r < 4; ++r) { mst[mi][r] = -1e30f; lst[mi][r] = 0.f; }
        oacc[mi][0] = (f32x4){0.f, 0.f, 0.f, 0.f};
        oacc[mi][1] = (f32x4){0.f, 0.f, 0.f, 0.f};
    }

    const float sc = 0.17677669529663687f; // 1/sqrt(32)
    for (int kt = 0; kt < 16; ++kt) {
        __syncthreads();
        {
            const int r = tid >> 2, c = tid & 3;
            int t = kt * 64 + r; if (t > 999) t = 999;
            const short* src = qkv + ((size_t)(b * TT_ + t)) * 768 + 256 + h * 32;
            s16x8 k8 = *(const s16x8*)(src + c * 8);
            *(s16x8*)(Ks + r * 40 + c * 8) = k8;
            s16x8 v8 = *(const s16x8*)(src + 256 + c * 8);
            #pragma unroll
            for (int j = 0; j < 8; ++j) Vt[(c * 8 + j) * 72 + r] = v8[j];
        }
        __syncthreads();

        // S = Q K^T  (A=Q rows, B=K rows as cols)
        f32x4 sf[2][4];
        #pragma unroll
        for (int ni = 0; ni < 4; ++ni) {
            const int kk = ni * 16 + l15;
            s16x8 bk = *(const s16x8*)(Ks + kk * 40 + lg * 8);
            #pragma unroll
            for (int mi = 0; mi < 2; ++mi) {
                f32x4 z = (f32x4){0.f, 0.f, 0.f, 0.f};
                sf[mi][ni] = __builtin_amdgcn_mfma_f32_16x16x32_bf16(aq[mi], bk, z, 0, 0, 0);
            }
        }

        #pragma unroll
        for (int mi = 0; mi < 2; ++mi) {
            #pragma unroll
            for (int ni = 0; ni < 4; ++ni) {
                const int colbase = kt * 64 + ni * 16 + l15;
                const bool valid = colbase < TT_;
                #pragma unroll
                for (int r = 0; r < 4; ++r)
                    sf[mi][ni][r] = valid ? sf[mi][ni][r] * sc : -1e30f;
            }
            #pragma unroll
            for (int r = 0; r < 4; ++r) {
                float mm = fmaxf(fmaxf(sf[mi][0][r], sf[mi][1][r]),
                                 fmaxf(sf[mi][2][r], sf[mi][3][r]));
                #pragma unroll
                for (int msk = 1; msk < 16; msk <<= 1) mm = fmaxf(mm, __shfl_xor(mm, msk));
                const float mn = fmaxf(mst[mi][r], mm);
                const float alpha = __expf(mst[mi][r] - mn);
                mst[mi][r] = mn;
                float ss = 0.f;
                #pragma unroll
                for (int ni = 0; ni < 4; ++ni) {
                    const float p = __expf(sf[mi][ni][r] - mn);
                    sf[mi][ni][r] = p; ss += p;
                }
                #pragma unroll
                for (int msk = 1; msk < 16; msk <<= 1) ss += __shfl_xor(ss, msk);
                lst[mi][r] = lst[mi][r] * alpha + ss;
                oacc[mi][0][r] *= alpha;
                oacc[mi][1][r] *= alpha;
            }
            // P -> per-wave LDS region (bf16, chunk-swizzled)
            #pragma unroll
            for (int ni = 0; ni < 4; ++ni) {
                const int kk = ni * 16 + l15;
                #pragma unroll
                for (int r = 0; r < 4; ++r) {
                    const int q = mi * 16 + lg * 4 + r;
                    Ps[wv][q * 64 + (((kk >> 3) ^ (q & 7)) * 8) + (kk & 7)] =
                        f2bf(sf[mi][ni][r]);
                }
            }
        }

        // O += P V   (A=P rows q, B=V^T cols d)
        #pragma unroll
        for (int ks = 0; ks < 2; ++ks) {
            s16x8 pa[2];
            #pragma unroll
            for (int mi = 0; mi < 2; ++mi) {
                const int q = mi * 16 + l15;
                const int ch = ks * 4 + lg;
                pa[mi] = *(const s16x8*)(&Ps[wv][q * 64 + ((ch ^ (q & 7)) * 8)]);
            }
            #pragma unroll
            for (int ni = 0; ni < 2; ++ni) {
                const int d = ni * 16 + l15;
                s16x8 bv = *(const s16x8*)(Vt + d * 72 + ks * 32 + lg * 8);
                #pragma unroll
                for (int mi = 0; mi < 2; ++mi)
                    oacc[mi][ni] = __builtin_amdgcn_mfma_f32_16x16x32_bf16(
                        pa[mi], bv, oacc[mi][ni], 0, 0, 0);
            }
        }
    }

    #pragma unroll
    for (int mi = 0; mi < 2; ++mi) {
        #pragma unroll
        for (int r = 0; r < 4; ++r) {
            const int t = q0 + mi * 16 + lg * 4 + r;
            if (t < TT_) {
                const float inv = 1.f / lst[mi][r];
                #pragma unroll
                for (int ni = 0; ni < 2; ++ni) {
                    const int d = ni * 16 + l15;
                    o[((size_t)(b * TT_ + t)) * 256 + h * 32 + d] =
                        f2bf(oacc[mi][ni][r] * inv);
                }
            }
        }
    }
}

// ---------------- token embedding + positional encoding (fp32 in, fp32+bf16 out) ----------------
__global__ __launch_bounds__(256) void embed_k(const float* __restrict__ Y,
                                               const float* __restrict__ W,
                                               const float* __restrict__ bias,
                                               float* __restrict__ X,
                                               short* __restrict__ Xb)
{
    __shared__ float As[16][68];
    __shared__ float Bs[16][68];
    const int tid = threadIdx.x;
    const int m0 = blockIdx.x * 64, n0 = blockIdx.y * 64;
    const int ty = tid >> 4, tx = tid & 15;
    const int la_m = tid >> 2, la_k = (tid & 3) * 4;
    const int lb_k = tid >> 4, lb_n = (tid & 15) * 4;

    const int rowA = m0 + la_m;
    const int bb = rowA / TT_, tt = rowA - bb * TT_;
    const float* yb = Y + (size_t)bb * NN_ * TTOT_ + NPAD_ + tt;

    float acc[4][4] = {};
    for (int k0 = 0; k0 < NN_; k0 += 16) {
        float a[4];
        #pragma unroll
        for (int j = 0; j < 4; ++j) a[j] = yb[(size_t)(k0 + la_k + j) * TTOT_];
        float4 b4 = *(const float4*)(W + (size_t)(k0 + lb_k) * DD_ + n0 + lb_n);
        __syncthreads();
        As[la_k + 0][la_m] = a[0]; As[la_k + 1][la_m] = a[1];
        As[la_k + 2][la_m] = a[2]; As[la_k + 3][la_m] = a[3];
        Bs[lb_k][lb_n + 0] = b4.x; Bs[lb_k][lb_n + 1] = b4.y;
        Bs[lb_k][lb_n + 2] = b4.z; Bs[lb_k][lb_n + 3] = b4.w;
        __syncthreads();
        #pragma unroll
        for (int k = 0; k < 16; ++k) {
            float ar[4], br[4];
            #pragma unroll
            for (int i = 0; i < 4; ++i) ar[i] = As[k][ty * 4 + i];
            #pragma unroll
            for (int j = 0; j < 4; ++j) br[j] = Bs[k][tx * 4 + j];
            #pragma unroll
            for (int i = 0; i < 4; ++i)
                #pragma unroll
                for (int j = 0; j < 4; ++j) acc[i][j] += ar[i] * br[j];
        }
    }
    #pragma unroll
    for (int i = 0; i < 4; ++i) {
        const int row = m0 + ty * 4 + i;
        const int t = row % TT_;
        #pragma unroll
        for (int j = 0; j < 4; ++j) {
            const int col = n0 + tx * 4 + j;
            float v = acc[i][j] + bias[col];
            const int i2 = col >> 1;
            const float div = expf(-(float)(2 * i2) * 0.0269834190585241f);
            const float ang = (float)t * div;
            v += (col & 1) ? cosf(ang) : sinf(ang);
            X[(size_t)row * DD_ + col] = v;
            Xb[(size_t)row * DD_ + col] = f2bf(v);
        }
    }
}

// ---------------- LayerNorm (fp32 in -> fp32 + bf16 out) ----------------
__global__ __launch_bounds__(256) void ln_k(const float* __restrict__ in,
                                            const float* __restrict__ g,
                                            const float* __restrict__ b,
                                            float* __restrict__ out,
                                            short* __restrict__ outb)
{
    const int row = blockIdx.x, d = threadIdx.x;
    const size_t base = (size_t)row * 256;
    const float v = in[base + d];
    float s = v;
    #pragma unroll
    for (int msk = 32; msk; msk >>= 1) s += __shfl_xor(s, msk);
    __shared__ float r1[4], r2[4];
    const int w = d >> 6;
    if ((d & 63) == 0) r1[w] = s;
    __syncthreads();
    const float mean = (r1[0] + r1[1] + r1[2] + r1[3]) * (1.f / 256.f);
    const float dv = v - mean;
    float q = dv * dv;
    #pragma unroll
    for (int msk = 32; msk; msk >>= 1) q += __shfl_xor(q, msk);
    if ((d & 63) == 0) r2[w] = q;
    __syncthreads();
    const float var = (r2[0] + r2[1] + r2[2] + r2[3]) * (1.f / 256.f);
    const float res = dv * rsqrtf(var + 1e-5f) * g[d] + b[d];
    out[base + d] = res;
    outb[base + d] = f2bf(res);
}

// ---------------- mean pool ----------------
__global__ __launch_bounds__(256) void pool_part_k(const float* __restrict__ X,
                                                   float* __restrict__ partial)
{
    const int b = blockIdx.x, seg = blockIdx.y, d = threadIdx.x;
    float s = 0.f;
    const int t0 = seg * 125;
    for (int t = t0; t < t0 + 125; ++t) s += X[((size_t)b * TT_ + t) * 256 + d];
    partial[(b * 8 + seg) * 256 + d] = s;
}
__global__ __launch_bounds__(256) void pool_red_k(const float* __restrict__ partial,
                                                  float* __restrict__ pooled)
{
    const int b = blockIdx.x, d = threadIdx.x;
    float s = 0.f;
    for (int k = 0; k < 8; ++k) s += partial[(b * 8 + k) * 256 + d];
    pooled[b * 256 + d] = s * (1.f / (float)TT_);
}

// ---------------- decode head ----------------
__global__ __launch_bounds__(128) void head_k(const float* __restrict__ pooled,
                                              const float* __restrict__ toLW,
                                              const float* __restrict__ toLb,
                                              const float* __restrict__ dW1,
                                              const float* __restrict__ db1,
                                              const float* __restrict__ dW2,
                                              const float* __restrict__ db2,
                                              float* __restrict__ coeffs)
{
    const int b = blockIdx.x, j = threadIdx.x;
    __shared__ float hs[64];
    __shared__ float hid[128];
    float a = toLb[j];
    for (int d = 0; d < 256; ++d) a += pooled[b * 256 + d] * toLW[d * 128 + j];
    if (j < 64) hs[j] = a;
    __syncthreads();
    float a2 = db1[j];
    for (int z = 0; z < 64; ++z) a2 += hs[z] * dW1[z * 128 + j];
    hid[j] = fmaxf(a2, 0.f);
    __syncthreads();
    if (j < 120) {
        float a3 = db2[j];
        for (int k = 0; k < 128; ++k) a3 += hid[k] * dW2[k * 120 + j];
        coeffs[b * 120 + j] = a3;
    }
}

// ---------------- combined conv kernel ----------------
__global__ void comb_k(const float* __restrict__ selfK,
                       const float* __restrict__ cplW,
                       const float* __restrict__ cplB,
                       float* __restrict__ comb)
{
    const int n = threadIdx.x;
    for (int ti = 0; ti < 20; ++ti) {
        float s = selfK[ti * 256 + n];
        #pragma unroll
        for (int si = 0; si < 4; ++si) s += cplW[n * 4 + si] * cplB[ti * 4 + si];
        comb[n * 20 + ti] = s;
    }
}

// ---------------- final ----------------
__global__ __launch_bounds__(256) void final_k(const float* __restrict__ Y,
                                               const float* __restrict__ SB,
                                               const float* __restrict__ roW,
                                               const float* __restrict__ coeffs,
                                               const float* __restrict__ comb,
                                               float* __restrict__ out)
{
    const int bx = blockIdx.x;
    const int b = bx >> 8, n = bx & 255;
    const int tid = threadIdx.x;
    __shared__ float w[30], ck[20];
    if (tid < 30) {
        float s = 0.f;
        #pragma unroll
        for (int f = 0; f < 4; ++f) s += roW[n * 4 + f] * coeffs[b * 120 + f * 30 + tid];
        w[tid] = s;
    }
    if (tid < 20) ck[tid] = comb[n * 20 + tid];
    __syncthreads();
    const float* yb = Y + ((size_t)b * 256 + n) * TTOT_;
    float* ob = out + ((size_t)b * 256 + n) * TT_;
    for (int t = tid; t < TT_; t += 256) {
        float acc = 0.f;
        const float* sb = SB + (size_t)t * 30;
        #pragma unroll
        for (int k = 0; k < 30; ++k) acc += w[k] * sb[k];
        #pragma unroll
        for (int tau = 1; tau <= 20; ++tau) acc += ck[tau - 1] * yb[t + NPAD_ - tau];
        ob[t] = acc;
    }
}

// ---------------- launch ----------------
extern "C" void kernel_launch(void* const* d_in, const int* in_sizes, int n_in,
                              void* d_out, int out_size, void* d_ws, size_t ws_size,
                              hipStream_t stream)
{
    const float* Y      = (const float*)d_in[0];
    const float* tokW   = (const float*)d_in[1];
    const float* tokb   = (const float*)d_in[2];
    const float* Wqkv   = (const float*)d_in[3];
    const float* bqkv   = (const float*)d_in[4];
    const float* Wo     = (const float*)d_in[5];
    const float* bo     = (const float*)d_in[6];
    const float* ln1g   = (const float*)d_in[7];
    const float* ln1b   = (const float*)d_in[8];
    const float* W1     = (const float*)d_in[9];
    const float* b1     = (const float*)d_in[10];
    const float* W2     = (const float*)d_in[11];
    const float* b2     = (const float*)d_in[12];
    const float* ln2g   = (const float*)d_in[13];
    const float* ln2b   = (const float*)d_in[14];
    const float* toLW   = (const float*)d_in[15];
    const float* toLb   = (const float*)d_in[16];
    const float* dW1    = (const float*)d_in[17];
    const float* db1    = (const float*)d_in[18];
    const float* dW2    = (const float*)d_in[19];
    const float* db2    = (const float*)d_in[20];
    const float* SB     = (const float*)d_in[21];
    const float* roW    = (const float*)d_in[22];
    const float* cplW   = (const float*)d_in[23];
    const float* cplB   = (const float*)d_in[24];
    const float* selfK  = (const float*)d_in[25];

    float* ws  = (float*)d_ws;
    float* X   = ws + X_OFF;
    short* Xb  = (short*)(ws + XB_OFF);
    short* O   = (short*)(ws + O_OFF);
    float* R   = ws + R_OFF;
    short* BIG = (short*)(ws + BIG_OFF);
    short* WT  = (short*)(ws + WT_OFF);
    float* PP  = ws + PP_OFF;
    float* PL  = ws + PL_OFF;
    float* CF  = ws + CF_OFF;
    float* CB  = ws + CB_OFF;

    short* WTqkv = WT;                 // 4 x 768x256
    short* WTo   = WT + 786432;        // 4 x 256x256
    short* WTw1  = WT + 1048576;       // 4 x 1024x256
    short* WTw2  = WT + 2097152;       // 4 x 256x1024

    // weight transpose-convert (fp32 KxN -> bf16 NxK)
    wtr_k<<<dim3(24, 8, 4), 256, 0, stream>>>(Wqkv, WTqkv, 256, 768);
    wtr_k<<<dim3(8, 8, 4),  256, 0, stream>>>(Wo,   WTo,   256, 256);
    wtr_k<<<dim3(32, 8, 4), 256, 0, stream>>>(W1,   WTw1,  256, 1024);
    wtr_k<<<dim3(8, 32, 4), 256, 0, stream>>>(W2,   WTw2,  1024, 256);

    embed_k<<<dim3(250, 4), 256, 0, stream>>>(Y, tokW, tokb, X, Xb);

    for (int l = 0; l < 4; ++l) {
        // qkv = Xb @ WqkvT^T + bqkv  -> bf16
        bgemm_k<1, 0, 0><<<dim3(125, 6), 256, 0, stream>>>(
            Xb, WTqkv + (size_t)l * 196608, bqkv + l * 768, nullptr, BIG,
            16000, 768, 256);
        mattn_k<<<dim3(8, 8, 16), 256, 0, stream>>>(BIG, O);
        // proj + resid -> fp32 R
        bgemm_k<0, 0, 1><<<dim3(125, 2), 256, 0, stream>>>(
            O, WTo + (size_t)l * 65536, bo + l * 256, X, R,
            16000, 256, 256);
        ln_k<<<16000, 256, 0, stream>>>(R, ln1g + l * 256, ln1b + l * 256, X, Xb);
        // ff1 + gelu -> bf16
        bgemm_k<1, 1, 0><<<dim3(125, 8), 256, 0, stream>>>(
            Xb, WTw1 + (size_t)l * 262144, b1 + l * 1024, nullptr, BIG,
            16000, 1024, 256);
        // ff2 + resid -> fp32 R
        bgemm_k<0, 0, 1><<<dim3(125, 2), 256, 0, stream>>>(
            BIG, WTw2 + (size_t)l * 262144, b2 + l * 256, X, R,
            16000, 256, 1024);
        ln_k<<<16000, 256, 0, stream>>>(R, ln2g + l * 256, ln2b + l * 256, X, Xb);
    }

    pool_part_k<<<dim3(16, 8), 256, 0, stream>>>(X, PP);
    pool_red_k<<<16, 256, 0, stream>>>(PP, PL);
    head_k<<<16, 128, 0, stream>>>(PL, toLW, toLb, dW1, db1, dW2, db2, CF);
    comb_k<<<1, 256, 0, stream>>>(selfK, cplW, cplB, CB);
    final_k<<<4096, 256, 0, stream>>>(Y, SB, roW, CF, CB, (float*)d_out);
}

// Round 3
// 785.430 us; speedup vs baseline: 4.2700x; 1.3879x over previous
//
#include <hip/hip_runtime.h>
#include <math.h>

// ---------------- problem constants ----------------
#define TT_   1000
#define TTOT_ 1100
#define NPAD_ 100
#define DD_   256
#define NN_   256

// workspace layout (float units)
#define X_OFF    0u           // fp32 residual stream 16000x256
#define XB_OFF   4096000u     // bf16 copy of X
#define O_OFF    6144000u     // bf16 attn out 16000x256
#define R_OFF    8192000u     // fp32 pre-LN buffer 16000x256
#define BIG_OFF  12288000u    // bf16 16000x1024 max
#define WT_OFF   20480000u    // bf16 transposed weights
#define PP_OFF   22052864u
#define PL_OFF   (PP_OFF + 32768u)
#define CF_OFF   (PL_OFF + 4096u)
#define CB_OFF   (CF_OFF + 1920u)

typedef __attribute__((ext_vector_type(8))) short s16x8;
typedef __attribute__((ext_vector_type(4))) float f32x4;
typedef __attribute__((ext_vector_type(16))) float f32x16;
typedef __attribute__((ext_vector_type(4))) unsigned u32x4;

__device__ inline short f2bf(float f) {
    unsigned u = __float_as_uint(f);
    u += 0x7fffu + ((u >> 16) & 1u);
    return (short)(u >> 16);
}

// ---------------- weight transpose-convert ----------------
__global__ __launch_bounds__(256) void wtr_k(const float* __restrict__ in,
                                             short* __restrict__ out, int K, int N)
{
    __shared__ float t[32][33];
    const int n0 = blockIdx.x * 32, k0 = blockIdx.y * 32;
    in  += (size_t)blockIdx.z * K * N;
    out += (size_t)blockIdx.z * K * N;
    const int tx = threadIdx.x & 31, ty = threadIdx.x >> 5;
    #pragma unroll
    for (int i = 0; i < 4; ++i)
        t[ty + 8 * i][tx] = in[(size_t)(k0 + ty + 8 * i) * N + n0 + tx];
    __syncthreads();
    #pragma unroll
    for (int i = 0; i < 4; ++i)
        out[(size_t)(n0 + ty + 8 * i) * K + k0 + tx] = f2bf(t[tx][ty + 8 * i]);
}

// ---------------- bf16 MFMA GEMM (128x128 tile, 4 waves) ----------------
template<int OUTBF, int ACT, int RES>
__global__ __launch_bounds__(256) void bgemm_k(const short* __restrict__ A,
                                               const short* __restrict__ Bt,
                                               const float* __restrict__ bias,
                                               const float* __restrict__ resid,
                                               void* __restrict__ Cout,
                                               int M, int N, int K)
{
    __shared__ short As[128 * 64];
    __shared__ short Bs[128 * 64];
    const int tid = threadIdx.x;
    const int m0 = blockIdx.x * 128, n0 = blockIdx.y * 128;
    const int wv = tid >> 6, lane = tid & 63;
    const int wr = wv >> 1, wc = wv & 1;
    const int l15 = lane & 15, lg = lane >> 4;

    f32x4 acc[4][4];
    #pragma unroll
    for (int i = 0; i < 4; ++i)
        #pragma unroll
        for (int j = 0; j < 4; ++j) acc[i][j] = (f32x4){0.f, 0.f, 0.f, 0.f};

    for (int k0 = 0; k0 < K; k0 += 64) {
        __syncthreads();
        #pragma unroll
        for (int i = 0; i < 4; ++i) {
            const int cid = tid + i * 256;
            const int r = cid >> 3, c = cid & 7;
            s16x8 av = *(const s16x8*)(A + (size_t)(m0 + r) * K + k0 + c * 8);
            *(s16x8*)(As + r * 64 + ((c ^ (r & 7)) * 8)) = av;
            s16x8 bv = *(const s16x8*)(Bt + (size_t)(n0 + r) * K + k0 + c * 8);
            *(s16x8*)(Bs + r * 64 + ((c ^ (r & 7)) * 8)) = bv;
        }
        __syncthreads();
        #pragma unroll
        for (int ks = 0; ks < 2; ++ks) {
            s16x8 af[4], bf[4];
            #pragma unroll
            for (int mi = 0; mi < 4; ++mi) {
                const int row = wr * 64 + mi * 16 + l15;
                const int ch = ks * 4 + lg;
                af[mi] = *(const s16x8*)(As + row * 64 + ((ch ^ (row & 7)) * 8));
            }
            #pragma unroll
            for (int ni = 0; ni < 4; ++ni) {
                const int col = wc * 64 + ni * 16 + l15;
                const int ch = ks * 4 + lg;
                bf[ni] = *(const s16x8*)(Bs + col * 64 + ((ch ^ (col & 7)) * 8));
            }
            #pragma unroll
            for (int mi = 0; mi < 4; ++mi)
                #pragma unroll
                for (int ni = 0; ni < 4; ++ni)
                    acc[mi][ni] = __builtin_amdgcn_mfma_f32_16x16x32_bf16(
                        af[mi], bf[ni], acc[mi][ni], 0, 0, 0);
        }
    }

    #pragma unroll
    for (int mi = 0; mi < 4; ++mi) {
        #pragma unroll
        for (int ni = 0; ni < 4; ++ni) {
            const int col = n0 + wc * 64 + ni * 16 + l15;
            const float bv = bias[col];
            #pragma unroll
            for (int r = 0; r < 4; ++r) {
                const int row = m0 + wr * 64 + mi * 16 + lg * 4 + r;
                float v = acc[mi][ni][r] + bv;
                if (RES) v += resid[(size_t)row * N + col];
                if (ACT) v = 0.5f * v * (1.0f + erff(v * 0.70710678118654752f));
                if (OUTBF) ((short*)Cout)[(size_t)row * N + col] = f2bf(v);
                else       ((float*)Cout)[(size_t)row * N + col] = v;
            }
        }
    }
}

// ---------------- MFMA flash attention, swapped-QK^T 32x32 structure ----------------
// qkv: (16*1000) x 768 bf16 rows [q|k|v], heads of 32. o: (16*1000) x 256 bf16.
// 4 waves x 32 q-rows = 128 q / block. KVBLK=64.
// S^T = K·Q^T (32x32x16 mfma x2 over d) -> lane holds 32 k-values for q=lane&31.
// Softmax in-register (1 shfl_xor(32) per reduce). P packed via v_cvt_pk_bf16_f32,
// redistributed with one shfl_xor(32) per word. PV as O^T = V^T·P.
__global__ __launch_bounds__(256) void mattn_k(const short* __restrict__ qkv,
                                               short* __restrict__ o)
{
    const int qt = blockIdx.x, h = blockIdx.y, b = blockIdx.z;
    const int tid = threadIdx.x, wv = tid >> 6, lane = tid & 63;
    const int q31 = lane & 31, hi = lane >> 5;
    __shared__ short Ks[64 * 40];   // K rows [64][40-stride]
    __shared__ short VT[32 * 72];   // V^T [d=32][72-stride], chunk-XOR swizzled

    // Q B-frag: col=q=lane&31, contraction d = dh*16 + hi*8 + j
    const int q0w = qt * 128 + wv * 32;
    int qrow = q0w + q31; if (qrow > 999) qrow = 999;
    s16x8 bq[2];
    #pragma unroll
    for (int dh = 0; dh < 2; ++dh)
        bq[dh] = *(const s16x8*)(qkv + ((size_t)(b * TT_ + qrow)) * 768 + h * 32 + dh * 16 + hi * 8);

    f32x16 oacc;
    #pragma unroll
    for (int i = 0; i < 16; ++i) oacc[i] = 0.f;
    float mrun = -1e30f, lrun = 0.f;
    const float sc = 0.17677669529663687f; // 1/sqrt(32)

    for (int kt = 0; kt < 16; ++kt) {
        __syncthreads();
        {   // stage K (b128, row-major stride 40) + V^T (scalar b16, swizzled)
            const int r = tid >> 2, c = tid & 3;
            int t = kt * 64 + r; if (t > 999) t = 999;
            const short* src = qkv + ((size_t)(b * TT_ + t)) * 768 + 256 + h * 32;
            s16x8 k8 = *(const s16x8*)(src + c * 8);
            *(s16x8*)(Ks + r * 40 + c * 8) = k8;
            s16x8 v8 = *(const s16x8*)(src + 256 + c * 8);
            #pragma unroll
            for (int j = 0; j < 8; ++j)
                VT[(c * 8 + j) * 72 + (((r >> 3) ^ c) * 8) + (r & 7)] = v8[j];
        }
        __syncthreads();

        // S^T[k][q] = sum_d K[k,d] Q[q,d]
        f32x16 st[2];
        #pragma unroll
        for (int kb = 0; kb < 2; ++kb) {
            s16x8 kf0 = *(const s16x8*)(Ks + (kb * 32 + q31) * 40 + hi * 8);
            s16x8 kf1 = *(const s16x8*)(Ks + (kb * 32 + q31) * 40 + 16 + hi * 8);
            f32x16 z;
            #pragma unroll
            for (int i = 0; i < 16; ++i) z[i] = 0.f;
            z = __builtin_amdgcn_mfma_f32_32x32x16_bf16(kf0, bq[0], z, 0, 0, 0);
            z = __builtin_amdgcn_mfma_f32_32x32x16_bf16(kf1, bq[1], z, 0, 0, 0);
            st[kb] = z;
        }
        // scale
        #pragma unroll
        for (int kb = 0; kb < 2; ++kb)
            #pragma unroll
            for (int r = 0; r < 16; ++r) st[kb][r] *= sc;
        // mask tail (k rows >= 1000) — only last tile
        if (kt == 15) {
            #pragma unroll
            for (int kb = 0; kb < 2; ++kb)
                #pragma unroll
                for (int r = 0; r < 16; ++r) {
                    const int kloc = kb * 32 + (r & 3) + 8 * (r >> 2) + 4 * hi;
                    if (960 + kloc >= TT_) st[kb][r] = -1e30f;
                }
        }
        // online softmax (row q = lane&31, split across lane/lane^32)
        float mloc = st[0][0];
        #pragma unroll
        for (int kb = 0; kb < 2; ++kb)
            #pragma unroll
            for (int r = 0; r < 16; ++r) mloc = fmaxf(mloc, st[kb][r]);
        mloc = fmaxf(mloc, __shfl_xor(mloc, 32));
        const float mn = fmaxf(mrun, mloc);
        const float alpha = __expf(mrun - mn);
        mrun = mn;
        float sloc = 0.f;
        #pragma unroll
        for (int kb = 0; kb < 2; ++kb)
            #pragma unroll
            for (int r = 0; r < 16; ++r) {
                const float p = __expf(st[kb][r] - mn);
                st[kb][r] = p; sloc += p;
            }
        sloc += __shfl_xor(sloc, 32);
        lrun = lrun * alpha + sloc;
        #pragma unroll
        for (int i = 0; i < 16; ++i) oacc[i] *= alpha;

        // pack P to bf16 pairs: wk[kb][a][h2] covers k2 = kb*32 + 8a + 4hi + 2h2
        unsigned wk[2][4][2];
        #pragma unroll
        for (int kb = 0; kb < 2; ++kb)
            #pragma unroll
            for (int a = 0; a < 4; ++a)
                #pragma unroll
                for (int h2 = 0; h2 < 2; ++h2) {
                    unsigned rr;
                    asm("v_cvt_pk_bf16_f32 %0, %1, %2"
                        : "=v"(rr)
                        : "v"(st[kb][4 * a + 2 * h2]), "v"(st[kb][4 * a + 2 * h2 + 1]));
                    wk[kb][a][h2] = rr;
                }

        // PV: O^T += V^T · P  (4 k-slots of 16)
        #pragma unroll
        for (int ks = 0; ks < 4; ++ks) {
            const int kb = ks >> 1, qq = ks & 1;
            unsigned W[4];
            #pragma unroll
            for (int h2 = 0; h2 < 2; ++h2) {
                const unsigned send = hi ? wk[kb][2 * qq][h2] : wk[kb][2 * qq + 1][h2];
                const unsigned recv = __shfl_xor(send, 32);
                W[h2]     = hi ? recv : wk[kb][2 * qq][h2];
                W[2 + h2] = hi ? wk[kb][2 * qq + 1][h2] : recv;
            }
            u32x4 w4 = (u32x4){W[0], W[1], W[2], W[3]};
            s16x8 pb = __builtin_bit_cast(s16x8, w4);
            s16x8 vf = *(const s16x8*)(VT + q31 * 72 + (((2 * ks + hi) ^ (q31 >> 3)) * 8));
            oacc = __builtin_amdgcn_mfma_f32_32x32x16_bf16(vf, pb, oacc, 0, 0, 0);
        }
    }

    // write O: lane owns column q (= t), rows d = crow(r,hi)
    const int t = q0w + q31;
    if (t < TT_) {
        const float inv = 1.f / lrun;
        short* ob = o + ((size_t)(b * TT_ + t)) * 256 + h * 32;
        #pragma unroll
        for (int a = 0; a < 4; ++a) {
            const int d0 = 8 * a + 4 * hi;
            short4 s4;
            s4.x = f2bf(oacc[4 * a + 0] * inv);
            s4.y = f2bf(oacc[4 * a + 1] * inv);
            s4.z = f2bf(oacc[4 * a + 2] * inv);
            s4.w = f2bf(oacc[4 * a + 3] * inv);
            *(short4*)(ob + d0) = s4;
        }
    }
}

// ---------------- token embedding + positional encoding ----------------
__global__ __launch_bounds__(256) void embed_k(const float* __restrict__ Y,
                                               const float* __restrict__ W,
                                               const float* __restrict__ bias,
                                               float* __restrict__ X,
                                               short* __restrict__ Xb)
{
    __shared__ float As[16][68];
    __shared__ float Bs[16][68];
    const int tid = threadIdx.x;
    const int m0 = blockIdx.x * 64, n0 = blockIdx.y * 64;
    const int ty = tid >> 4, tx = tid & 15;
    const int la_m = tid >> 2, la_k = (tid & 3) * 4;
    const int lb_k = tid >> 4, lb_n = (tid & 15) * 4;

    const int rowA = m0 + la_m;
    const int bb = rowA / TT_, tt = rowA - bb * TT_;
    const float* yb = Y + (size_t)bb * NN_ * TTOT_ + NPAD_ + tt;

    float acc[4][4] = {};
    for (int k0 = 0; k0 < NN_; k0 += 16) {
        float a[4];
        #pragma unroll
        for (int j = 0; j < 4; ++j) a[j] = yb[(size_t)(k0 + la_k + j) * TTOT_];
        float4 b4 = *(const float4*)(W + (size_t)(k0 + lb_k) * DD_ + n0 + lb_n);
        __syncthreads();
        As[la_k + 0][la_m] = a[0]; As[la_k + 1][la_m] = a[1];
        As[la_k + 2][la_m] = a[2]; As[la_k + 3][la_m] = a[3];
        Bs[lb_k][lb_n + 0] = b4.x; Bs[lb_k][lb_n + 1] = b4.y;
        Bs[lb_k][lb_n + 2] = b4.z; Bs[lb_k][lb_n + 3] = b4.w;
        __syncthreads();
        #pragma unroll
        for (int k = 0; k < 16; ++k) {
            float ar[4], br[4];
            #pragma unroll
            for (int i = 0; i < 4; ++i) ar[i] = As[k][ty * 4 + i];
            #pragma unroll
            for (int j = 0; j < 4; ++j) br[j] = Bs[k][tx * 4 + j];
            #pragma unroll
            for (int i = 0; i < 4; ++i)
                #pragma unroll
                for (int j = 0; j < 4; ++j) acc[i][j] += ar[i] * br[j];
        }
    }
    #pragma unroll
    for (int i = 0; i < 4; ++i) {
        const int row = m0 + ty * 4 + i;
        const int t = row % TT_;
        #pragma unroll
        for (int j = 0; j < 4; ++j) {
            const int col = n0 + tx * 4 + j;
            float v = acc[i][j] + bias[col];
            const int i2 = col >> 1;
            const float div = expf(-(float)(2 * i2) * 0.0269834190585241f);
            const float ang = (float)t * div;
            v += (col & 1) ? cosf(ang) : sinf(ang);
            X[(size_t)row * DD_ + col] = v;
            Xb[(size_t)row * DD_ + col] = f2bf(v);
        }
    }
}

// ---------------- LayerNorm ----------------
__global__ __launch_bounds__(256) void ln_k(const float* __restrict__ in,
                                            const float* __restrict__ g,
                                            const float* __restrict__ b,
                                            float* __restrict__ out,
                                            short* __restrict__ outb)
{
    const int row = blockIdx.x, d = threadIdx.x;
    const size_t base = (size_t)row * 256;
    const float v = in[base + d];
    float s = v;
    #pragma unroll
    for (int msk = 32; msk; msk >>= 1) s += __shfl_xor(s, msk);
    __shared__ float r1[4], r2[4];
    const int w = d >> 6;
    if ((d & 63) == 0) r1[w] = s;
    __syncthreads();
    const float mean = (r1[0] + r1[1] + r1[2] + r1[3]) * (1.f / 256.f);
    const float dv = v - mean;
    float q = dv * dv;
    #pragma unroll
    for (int msk = 32; msk; msk >>= 1) q += __shfl_xor(q, msk);
    if ((d & 63) == 0) r2[w] = q;
    __syncthreads();
    const float var = (r2[0] + r2[1] + r2[2] + r2[3]) * (1.f / 256.f);
    const float res = dv * rsqrtf(var + 1e-5f) * g[d] + b[d];
    out[base + d] = res;
    outb[base + d] = f2bf(res);
}

// ---------------- mean pool ----------------
__global__ __launch_bounds__(256) void pool_part_k(const float* __restrict__ X,
                                                   float* __restrict__ partial)
{
    const int b = blockIdx.x, seg = blockIdx.y, d = threadIdx.x;
    float s = 0.f;
    const int t0 = seg * 125;
    for (int t = t0; t < t0 + 125; ++t) s += X[((size_t)b * TT_ + t) * 256 + d];
    partial[(b * 8 + seg) * 256 + d] = s;
}
__global__ __launch_bounds__(256) void pool_red_k(const float* __restrict__ partial,
                                                  float* __restrict__ pooled)
{
    const int b = blockIdx.x, d = threadIdx.x;
    float s = 0.f;
    for (int k = 0; k < 8; ++k) s += partial[(b * 8 + k) * 256 + d];
    pooled[b * 256 + d] = s * (1.f / (float)TT_);
}

// ---------------- decode head ----------------
__global__ __launch_bounds__(128) void head_k(const float* __restrict__ pooled,
                                              const float* __restrict__ toLW,
                                              const float* __restrict__ toLb,
                                              const float* __restrict__ dW1,
                                              const float* __restrict__ db1,
                                              const float* __restrict__ dW2,
                                              const float* __restrict__ db2,
                                              float* __restrict__ coeffs)
{
    const int b = blockIdx.x, j = threadIdx.x;
    __shared__ float hs[64];
    __shared__ float hid[128];
    float a = toLb[j];
    for (int d = 0; d < 256; ++d) a += pooled[b * 256 + d] * toLW[d * 128 + j];
    if (j < 64) hs[j] = a;
    __syncthreads();
    float a2 = db1[j];
    for (int z = 0; z < 64; ++z) a2 += hs[z] * dW1[z * 128 + j];
    hid[j] = fmaxf(a2, 0.f);
    __syncthreads();
    if (j < 120) {
        float a3 = db2[j];
        for (int k = 0; k < 128; ++k) a3 += hid[k] * dW2[k * 120 + j];
        coeffs[b * 120 + j] = a3;
    }
}

// ---------------- combined conv kernel ----------------
__global__ void comb_k(const float* __restrict__ selfK,
                       const float* __restrict__ cplW,
                       const float* __restrict__ cplB,
                       float* __restrict__ comb)
{
    const int n = threadIdx.x;
    for (int ti = 0; ti < 20; ++ti) {
        float s = selfK[ti * 256 + n];
        #pragma unroll
        for (int si = 0; si < 4; ++si) s += cplW[n * 4 + si] * cplB[ti * 4 + si];
        comb[n * 20 + ti] = s;
    }
}

// ---------------- final ----------------
__global__ __launch_bounds__(256) void final_k(const float* __restrict__ Y,
                                               const float* __restrict__ SB,
                                               const float* __restrict__ roW,
                                               const float* __restrict__ coeffs,
                                               const float* __restrict__ comb,
                                               float* __restrict__ out)
{
    const int bx = blockIdx.x;
    const int b = bx >> 8, n = bx & 255;
    const int tid = threadIdx.x;
    __shared__ float w[30], ck[20];
    if (tid < 30) {
        float s = 0.f;
        #pragma unroll
        for (int f = 0; f < 4; ++f) s += roW[n * 4 + f] * coeffs[b * 120 + f * 30 + tid];
        w[tid] = s;
    }
    if (tid < 20) ck[tid] = comb[n * 20 + tid];
    __syncthreads();
    const float* yb = Y + ((size_t)b * 256 + n) * TTOT_;
    float* ob = out + ((size_t)b * 256 + n) * TT_;
    for (int t = tid; t < TT_; t += 256) {
        float acc = 0.f;
        const float* sb = SB + (size_t)t * 30;
        #pragma unroll
        for (int k = 0; k < 30; ++k) acc += w[k] * sb[k];
        #pragma unroll
        for (int tau = 1; tau <= 20; ++tau) acc += ck[tau - 1] * yb[t + NPAD_ - tau];
        ob[t] = acc;
    }
}

// ---------------- launch ----------------
extern "C" void kernel_launch(void* const* d_in, const int* in_sizes, int n_in,
                              void* d_out, int out_size, void* d_ws, size_t ws_size,
                              hipStream_t stream)
{
    const float* Y      = (const float*)d_in[0];
    const float* tokW   = (const float*)d_in[1];
    const float* tokb   = (const float*)d_in[2];
    const float* Wqkv   = (const float*)d_in[3];
    const float* bqkv   = (const float*)d_in[4];
    const float* Wo     = (const float*)d_in[5];
    const float* bo     = (const float*)d_in[6];
    const float* ln1g   = (const float*)d_in[7];
    const float* ln1b   = (const float*)d_in[8];
    const float* W1     = (const float*)d_in[9];
    const float* b1     = (const float*)d_in[10];
    const float* W2     = (const float*)d_in[11];
    const float* b2     = (const float*)d_in[12];
    const float* ln2g   = (const float*)d_in[13];
    const float* ln2b   = (const float*)d_in[14];
    const float* toLW   = (const float*)d_in[15];
    const float* toLb   = (const float*)d_in[16];
    const float* dW1    = (const float*)d_in[17];
    const float* db1    = (const float*)d_in[18];
    const float* dW2    = (const float*)d_in[19];
    const float* db2    = (const float*)d_in[20];
    const float* SB     = (const float*)d_in[21];
    const float* roW    = (const float*)d_in[22];
    const float* cplW   = (const float*)d_in[23];
    const float* cplB   = (const float*)d_in[24];
    const float* selfK  = (const float*)d_in[25];

    float* ws  = (float*)d_ws;
    float* X   = ws + X_OFF;
    short* Xb  = (short*)(ws + XB_OFF);
    short* O   = (short*)(ws + O_OFF);
    float* R   = ws + R_OFF;
    short* BIG = (short*)(ws + BIG_OFF);
    short* WT  = (short*)(ws + WT_OFF);
    float* PP  = ws + PP_OFF;
    float* PL  = ws + PL_OFF;
    float* CF  = ws + CF_OFF;
    float* CB  = ws + CB_OFF;

    short* WTqkv = WT;                 // 4 x 768x256
    short* WTo   = WT + 786432;        // 4 x 256x256
    short* WTw1  = WT + 1048576;       // 4 x 1024x256
    short* WTw2  = WT + 2097152;       // 4 x 256x1024

    wtr_k<<<dim3(24, 8, 4), 256, 0, stream>>>(Wqkv, WTqkv, 256, 768);
    wtr_k<<<dim3(8, 8, 4),  256, 0, stream>>>(Wo,   WTo,   256, 256);
    wtr_k<<<dim3(32, 8, 4), 256, 0, stream>>>(W1,   WTw1,  256, 1024);
    wtr_k<<<dim3(8, 32, 4), 256, 0, stream>>>(W2,   WTw2,  1024, 256);

    embed_k<<<dim3(250, 4), 256, 0, stream>>>(Y, tokW, tokb, X, Xb);

    for (int l = 0; l < 4; ++l) {
        bgemm_k<1, 0, 0><<<dim3(125, 6), 256, 0, stream>>>(
            Xb, WTqkv + (size_t)l * 196608, bqkv + l * 768, nullptr, BIG,
            16000, 768, 256);
        mattn_k<<<dim3(8, 8, 16), 256, 0, stream>>>(BIG, O);
        bgemm_k<0, 0, 1><<<dim3(125, 2), 256, 0, stream>>>(
            O, WTo + (size_t)l * 65536, bo + l * 256, X, R,
            16000, 256, 256);
        ln_k<<<16000, 256, 0, stream>>>(R, ln1g + l * 256, ln1b + l * 256, X, Xb);
        bgemm_k<1, 1, 0><<<dim3(125, 8), 256, 0, stream>>>(
            Xb, WTw1 + (size_t)l * 262144, b1 + l * 1024, nullptr, BIG,
            16000, 1024, 256);
        bgemm_k<0, 0, 1><<<dim3(125, 2), 256, 0, stream>>>(
            BIG, WTw2 + (size_t)l * 262144, b2 + l * 256, X, R,
            16000, 256, 1024);
        ln_k<<<16000, 256, 0, stream>>>(R, ln2g + l * 256, ln2b + l * 256, X, Xb);
    }

    pool_part_k<<<dim3(16, 8), 256, 0, stream>>>(X, PP);
    pool_red_k<<<16, 256, 0, stream>>>(PP, PL);
    head_k<<<16, 128, 0, stream>>>(PL, toLW, toLb, dW1, db1, dW2, db2, CF);
    comb_k<<<1, 256, 0, stream>>>(selfK, cplW, cplB, CB);
    final_k<<<4096, 256, 0, stream>>>(Y, SB, roW, CF, CB, (float*)d_out);
}

// Round 4
// 675.116 us; speedup vs baseline: 4.9677x; 1.1634x over previous
//
#include <hip/hip_runtime.h>
#include <math.h>

// ---------------- problem constants ----------------
#define TT_   1000
#define TTOT_ 1100
#define NPAD_ 100
#define DD_   256
#define NN_   256

// workspace layout (float units)
#define X_OFF    0u           // fp32 residual stream 16000x256
#define XB_OFF   4096000u     // bf16 copy of X
#define O_OFF    6144000u     // bf16 attn out 16000x256
#define R_OFF    8192000u     // fp32 pre-LN buffer 16000x256
#define BIG_OFF  12288000u    // bf16 16000x1024 max
#define WT_OFF   20480000u    // bf16 transposed weights
#define PP_OFF   22052864u
#define PL_OFF   (PP_OFF + 32768u)
#define CF_OFF   (PL_OFF + 4096u)
#define CB_OFF   (CF_OFF + 1920u)

typedef __attribute__((ext_vector_type(8))) short s16x8;
typedef __attribute__((ext_vector_type(4))) float f32x4;
typedef __attribute__((ext_vector_type(16))) float f32x16;
typedef __attribute__((ext_vector_type(4))) unsigned u32x4;

__device__ inline short f2bf(float f) {
    unsigned u = __float_as_uint(f);
    u += 0x7fffu + ((u >> 16) & 1u);
    return (short)(u >> 16);
}

// async global->LDS, 16B per lane. LDS dest must be linear in lane order.
__device__ inline void gl_lds16(const short* g, short* l) {
    __builtin_amdgcn_global_load_lds(
        (const __attribute__((address_space(1))) void*)g,
        (__attribute__((address_space(3))) void*)l, 16, 0, 0);
}

// ---------------- weight transpose-convert ----------------
__global__ __launch_bounds__(256) void wtr_k(const float* __restrict__ in,
                                             short* __restrict__ out, int K, int N)
{
    __shared__ float t[32][33];
    const int n0 = blockIdx.x * 32, k0 = blockIdx.y * 32;
    in  += (size_t)blockIdx.z * K * N;
    out += (size_t)blockIdx.z * K * N;
    const int tx = threadIdx.x & 31, ty = threadIdx.x >> 5;
    #pragma unroll
    for (int i = 0; i < 4; ++i)
        t[ty + 8 * i][tx] = in[(size_t)(k0 + ty + 8 * i) * N + n0 + tx];
    __syncthreads();
    #pragma unroll
    for (int i = 0; i < 4; ++i)
        out[(size_t)(n0 + ty + 8 * i) * K + k0 + tx] = f2bf(t[tx][ty + 8 * i]);
}

// ---------------- bf16 MFMA GEMM (128x128 tile, 4 waves) ----------------
// 2-phase double-buffered global_load_lds pipeline; bijective XCD swizzle,
// column-fast decomposition (all nby column-blocks of an A-panel on one XCD).
template<int OUTBF, int ACT, int RES>
__global__ __launch_bounds__(256) void bgemm_k(const short* __restrict__ A,
                                               const short* __restrict__ Bt,
                                               const float* __restrict__ bias,
                                               const float* __restrict__ resid,
                                               void* __restrict__ Cout,
                                               int M, int N, int K, int nby)
{
    __shared__ short SH[4 * 8192];   // 2 buffers x (A 128x64 | B 128x64)
    const int tid = threadIdx.x;

    // bijective XCD swizzle
    const int nwg = gridDim.x;
    int gid = blockIdx.x;
    {
        const int q = nwg >> 3, r = nwg & 7;
        const int x = gid & 7, idx = gid >> 3;
        gid = (x < r ? x * (q + 1) : r * (q + 1) + (x - r) * q) + idx;
    }
    const int bx = gid / nby, by = gid - bx * nby;
    const int m0 = bx * 128, n0 = by * 128;

    const int wv = tid >> 6, lane = tid & 63;
    const int wr = wv >> 1, wc = wv & 1;
    const int l15 = lane & 15, lg = lane >> 4;

    f32x4 acc[4][4];
    #pragma unroll
    for (int i = 0; i < 4; ++i)
        #pragma unroll
        for (int j = 0; j < 4; ++j) acc[i][j] = (f32x4){0.f, 0.f, 0.f, 0.f};

    const int nt = K >> 6;

    // stage: LDS linear (cid*8 shorts), global source chunk pre-swizzled so a
    // ds_read at chunk (ch ^ (row&7)) yields global chunk ch.
    auto STAGE = [&](int p, int k0) {
        short* dstA = (short*)SH + p * 16384;
        short* dstB = dstA + 8192;
        #pragma unroll
        for (int i = 0; i < 4; ++i) {
            const int cid = i * 256 + tid;
            const int r = cid >> 3, c = cid & 7;
            const int sc = ((c ^ (r & 7)) * 8);
            gl_lds16(A + (size_t)(m0 + r) * K + k0 + sc, dstA + cid * 8);
            gl_lds16(Bt + (size_t)(n0 + r) * K + k0 + sc, dstB + cid * 8);
        }
    };

    STAGE(0, 0);
    asm volatile("s_waitcnt vmcnt(0)" ::: "memory");
    __builtin_amdgcn_s_barrier();

    int cur = 0;
    for (int t = 0; t < nt; ++t) {
        if (t + 1 < nt) STAGE(cur ^ 1, (t + 1) << 6);

        const short* Asb = (const short*)SH + cur * 16384;
        const short* Bsb = Asb + 8192;
        #pragma unroll
        for (int ks = 0; ks < 2; ++ks) {
            s16x8 af[4], bf[4];
            #pragma unroll
            for (int mi = 0; mi < 4; ++mi) {
                const int row = wr * 64 + mi * 16 + l15;
                const int ch = ks * 4 + lg;
                af[mi] = *(const s16x8*)(Asb + row * 64 + ((ch ^ (row & 7)) * 8));
            }
            #pragma unroll
            for (int ni = 0; ni < 4; ++ni) {
                const int col = wc * 64 + ni * 16 + l15;
                const int ch = ks * 4 + lg;
                bf[ni] = *(const s16x8*)(Bsb + col * 64 + ((ch ^ (col & 7)) * 8));
            }
            #pragma unroll
            for (int mi = 0; mi < 4; ++mi)
                #pragma unroll
                for (int ni = 0; ni < 4; ++ni)
                    acc[mi][ni] = __builtin_amdgcn_mfma_f32_16x16x32_bf16(
                        af[mi], bf[ni], acc[mi][ni], 0, 0, 0);
        }
        asm volatile("s_waitcnt vmcnt(0)" ::: "memory");
        __builtin_amdgcn_s_barrier();
        cur ^= 1;
    }

    #pragma unroll
    for (int mi = 0; mi < 4; ++mi) {
        #pragma unroll
        for (int ni = 0; ni < 4; ++ni) {
            const int col = n0 + wc * 64 + ni * 16 + l15;
            const float bv = bias[col];
            #pragma unroll
            for (int r = 0; r < 4; ++r) {
                const int row = m0 + wr * 64 + mi * 16 + lg * 4 + r;
                float v = acc[mi][ni][r] + bv;
                if (RES) v += resid[(size_t)row * N + col];
                if (ACT) v = 0.5f * v * (1.0f + erff(v * 0.70710678118654752f));
                if (OUTBF) ((short*)Cout)[(size_t)row * N + col] = f2bf(v);
                else       ((float*)Cout)[(size_t)row * N + col] = v;
            }
        }
    }
}

// ---------------- MFMA flash attention, swapped-QK^T 32x32 structure ----------------
__global__ __launch_bounds__(256) void mattn_k(const short* __restrict__ qkv,
                                               short* __restrict__ o)
{
    // XCD swizzle over 1024 blocks: each XCD gets 128 contiguous (qt,h,b) ids
    int wg = blockIdx.x;
    wg = (wg & 7) * 128 + (wg >> 3);
    const int qt = wg & 7, h = (wg >> 3) & 7, b = wg >> 6;

    const int tid = threadIdx.x, wv = tid >> 6, lane = tid & 63;
    const int q31 = lane & 31, hi = lane >> 5;
    __shared__ short Ks[64 * 40];
    __shared__ short VT[32 * 72];

    const int q0w = qt * 128 + wv * 32;
    int qrow = q0w + q31; if (qrow > 999) qrow = 999;
    s16x8 bq[2];
    #pragma unroll
    for (int dh = 0; dh < 2; ++dh)
        bq[dh] = *(const s16x8*)(qkv + ((size_t)(b * TT_ + qrow)) * 768 + h * 32 + dh * 16 + hi * 8);

    f32x16 oacc;
    #pragma unroll
    for (int i = 0; i < 16; ++i) oacc[i] = 0.f;
    float mrun = -1e30f, lrun = 0.f;
    const float sc = 0.17677669529663687f;

    for (int kt = 0; kt < 16; ++kt) {
        __syncthreads();
        {
            const int r = tid >> 2, c = tid & 3;
            int t = kt * 64 + r; if (t > 999) t = 999;
            const short* src = qkv + ((size_t)(b * TT_ + t)) * 768 + 256 + h * 32;
            s16x8 k8 = *(const s16x8*)(src + c * 8);
            *(s16x8*)(Ks + r * 40 + c * 8) = k8;
            s16x8 v8 = *(const s16x8*)(src + 256 + c * 8);
            #pragma unroll
            for (int j = 0; j < 8; ++j)
                VT[(c * 8 + j) * 72 + (((r >> 3) ^ c) * 8) + (r & 7)] = v8[j];
        }
        __syncthreads();

        f32x16 st[2];
        #pragma unroll
        for (int kb = 0; kb < 2; ++kb) {
            s16x8 kf0 = *(const s16x8*)(Ks + (kb * 32 + q31) * 40 + hi * 8);
            s16x8 kf1 = *(const s16x8*)(Ks + (kb * 32 + q31) * 40 + 16 + hi * 8);
            f32x16 z;
            #pragma unroll
            for (int i = 0; i < 16; ++i) z[i] = 0.f;
            z = __builtin_amdgcn_mfma_f32_32x32x16_bf16(kf0, bq[0], z, 0, 0, 0);
            z = __builtin_amdgcn_mfma_f32_32x32x16_bf16(kf1, bq[1], z, 0, 0, 0);
            st[kb] = z;
        }
        #pragma unroll
        for (int kb = 0; kb < 2; ++kb)
            #pragma unroll
            for (int r = 0; r < 16; ++r) st[kb][r] *= sc;
        if (kt == 15) {
            #pragma unroll
            for (int kb = 0; kb < 2; ++kb)
                #pragma unroll
                for (int r = 0; r < 16; ++r) {
                    const int kloc = kb * 32 + (r & 3) + 8 * (r >> 2) + 4 * hi;
                    if (960 + kloc >= TT_) st[kb][r] = -1e30f;
                }
        }
        float mloc = st[0][0];
        #pragma unroll
        for (int kb = 0; kb < 2; ++kb)
            #pragma unroll
            for (int r = 0; r < 16; ++r) mloc = fmaxf(mloc, st[kb][r]);
        mloc = fmaxf(mloc, __shfl_xor(mloc, 32));
        const float mn = fmaxf(mrun, mloc);
        const float alpha = __expf(mrun - mn);
        mrun = mn;
        float sloc = 0.f;
        #pragma unroll
        for (int kb = 0; kb < 2; ++kb)
            #pragma unroll
            for (int r = 0; r < 16; ++r) {
                const float p = __expf(st[kb][r] - mn);
                st[kb][r] = p; sloc += p;
            }
        sloc += __shfl_xor(sloc, 32);
        lrun = lrun * alpha + sloc;
        #pragma unroll
        for (int i = 0; i < 16; ++i) oacc[i] *= alpha;

        unsigned wk[2][4][2];
        #pragma unroll
        for (int kb = 0; kb < 2; ++kb)
            #pragma unroll
            for (int a = 0; a < 4; ++a)
                #pragma unroll
                for (int h2 = 0; h2 < 2; ++h2) {
                    unsigned rr;
                    asm("v_cvt_pk_bf16_f32 %0, %1, %2"
                        : "=v"(rr)
                        : "v"(st[kb][4 * a + 2 * h2]), "v"(st[kb][4 * a + 2 * h2 + 1]));
                    wk[kb][a][h2] = rr;
                }

        #pragma unroll
        for (int ks = 0; ks < 4; ++ks) {
            const int kb = ks >> 1, qq = ks & 1;
            unsigned W[4];
            #pragma unroll
            for (int h2 = 0; h2 < 2; ++h2) {
                const unsigned send = hi ? wk[kb][2 * qq][h2] : wk[kb][2 * qq + 1][h2];
                const unsigned recv = __shfl_xor(send, 32);
                W[h2]     = hi ? recv : wk[kb][2 * qq][h2];
                W[2 + h2] = hi ? wk[kb][2 * qq + 1][h2] : recv;
            }
            u32x4 w4 = (u32x4){W[0], W[1], W[2], W[3]};
            s16x8 pb = __builtin_bit_cast(s16x8, w4);
            s16x8 vf = *(const s16x8*)(VT + q31 * 72 + (((2 * ks + hi) ^ (q31 >> 3)) * 8));
            oacc = __builtin_amdgcn_mfma_f32_32x32x16_bf16(vf, pb, oacc, 0, 0, 0);
        }
    }

    const int t = q0w + q31;
    if (t < TT_) {
        const float inv = 1.f / lrun;
        short* ob = o + ((size_t)(b * TT_ + t)) * 256 + h * 32;
        #pragma unroll
        for (int a = 0; a < 4; ++a) {
            const int d0 = 8 * a + 4 * hi;
            short4 s4;
            s4.x = f2bf(oacc[4 * a + 0] * inv);
            s4.y = f2bf(oacc[4 * a + 1] * inv);
            s4.z = f2bf(oacc[4 * a + 2] * inv);
            s4.w = f2bf(oacc[4 * a + 3] * inv);
            *(short4*)(ob + d0) = s4;
        }
    }
}

// ---------------- token embedding + positional encoding ----------------
__global__ __launch_bounds__(256) void embed_k(const float* __restrict__ Y,
                                               const float* __restrict__ W,
                                               const float* __restrict__ bias,
                                               float* __restrict__ X,
                                               short* __restrict__ Xb)
{
    __shared__ float As[16][68];
    __shared__ float Bs[16][68];
    const int tid = threadIdx.x;
    const int m0 = blockIdx.x * 64, n0 = blockIdx.y * 64;
    const int ty = tid >> 4, tx = tid & 15;
    const int la_m = tid >> 2, la_k = (tid & 3) * 4;
    const int lb_k = tid >> 4, lb_n = (tid & 15) * 4;

    const int rowA = m0 + la_m;
    const int bb = rowA / TT_, tt = rowA - bb * TT_;
    const float* yb = Y + (size_t)bb * NN_ * TTOT_ + NPAD_ + tt;

    float acc[4][4] = {};
    for (int k0 = 0; k0 < NN_; k0 += 16) {
        float a[4];
        #pragma unroll
        for (int j = 0; j < 4; ++j) a[j] = yb[(size_t)(k0 + la_k + j) * TTOT_];
        float4 b4 = *(const float4*)(W + (size_t)(k0 + lb_k) * DD_ + n0 + lb_n);
        __syncthreads();
        As[la_k + 0][la_m] = a[0]; As[la_k + 1][la_m] = a[1];
        As[la_k + 2][la_m] = a[2]; As[la_k + 3][la_m] = a[3];
        Bs[lb_k][lb_n + 0] = b4.x; Bs[lb_k][lb_n + 1] = b4.y;
        Bs[lb_k][lb_n + 2] = b4.z; Bs[lb_k][lb_n + 3] = b4.w;
        __syncthreads();
        #pragma unroll
        for (int k = 0; k < 16; ++k) {
            float ar[4], br[4];
            #pragma unroll
            for (int i = 0; i < 4; ++i) ar[i] = As[k][ty * 4 + i];
            #pragma unroll
            for (int j = 0; j < 4; ++j) br[j] = Bs[k][tx * 4 + j];
            #pragma unroll
            for (int i = 0; i < 4; ++i)
                #pragma unroll
                for (int j = 0; j < 4; ++j) acc[i][j] += ar[i] * br[j];
        }
    }
    #pragma unroll
    for (int i = 0; i < 4; ++i) {
        const int row = m0 + ty * 4 + i;
        const int t = row % TT_;
        #pragma unroll
        for (int j = 0; j < 4; ++j) {
            const int col = n0 + tx * 4 + j;
            float v = acc[i][j] + bias[col];
            const int i2 = col >> 1;
            const float div = expf(-(float)(2 * i2) * 0.0269834190585241f);
            const float ang = (float)t * div;
            v += (col & 1) ? cosf(ang) : sinf(ang);
            X[(size_t)row * DD_ + col] = v;
            Xb[(size_t)row * DD_ + col] = f2bf(v);
        }
    }
}

// ---------------- LayerNorm: 4 rows/block, 1 wave/row, float4 ----------------
__global__ __launch_bounds__(256) void ln_k(const float* __restrict__ in,
                                            const float* __restrict__ g,
                                            const float* __restrict__ b,
                                            float* __restrict__ out,
                                            short* __restrict__ outb)
{
    const int row = blockIdx.x * 4 + (threadIdx.x >> 6);
    const int lane = threadIdx.x & 63;
    const size_t base = (size_t)row * 256 + lane * 4;
    float4 v = *(const float4*)(in + base);
    float s = v.x + v.y + v.z + v.w;
    #pragma unroll
    for (int msk = 1; msk < 64; msk <<= 1) s += __shfl_xor(s, msk);
    const float mean = s * (1.f / 256.f);
    float4 d; d.x = v.x - mean; d.y = v.y - mean; d.z = v.z - mean; d.w = v.w - mean;
    float q = d.x * d.x + d.y * d.y + d.z * d.z + d.w * d.w;
    #pragma unroll
    for (int msk = 1; msk < 64; msk <<= 1) q += __shfl_xor(q, msk);
    const float rs = rsqrtf(q * (1.f / 256.f) + 1e-5f);
    const float4 g4 = *(const float4*)(g + lane * 4);
    const float4 b4 = *(const float4*)(b + lane * 4);
    float4 o4;
    o4.x = d.x * rs * g4.x + b4.x;
    o4.y = d.y * rs * g4.y + b4.y;
    o4.z = d.z * rs * g4.z + b4.z;
    o4.w = d.w * rs * g4.w + b4.w;
    *(float4*)(out + base) = o4;
    short4 s4;
    s4.x = f2bf(o4.x); s4.y = f2bf(o4.y); s4.z = f2bf(o4.z); s4.w = f2bf(o4.w);
    *(short4*)(outb + base) = s4;
}

// ---------------- mean pool ----------------
__global__ __launch_bounds__(256) void pool_part_k(const float* __restrict__ X,
                                                   float* __restrict__ partial)
{
    const int b = blockIdx.x, seg = blockIdx.y, d = threadIdx.x;
    float s = 0.f;
    const int t0 = seg * 125;
    for (int t = t0; t < t0 + 125; ++t) s += X[((size_t)b * TT_ + t) * 256 + d];
    partial[(b * 8 + seg) * 256 + d] = s;
}
__global__ __launch_bounds__(256) void pool_red_k(const float* __restrict__ partial,
                                                  float* __restrict__ pooled)
{
    const int b = blockIdx.x, d = threadIdx.x;
    float s = 0.f;
    for (int k = 0; k < 8; ++k) s += partial[(b * 8 + k) * 256 + d];
    pooled[b * 256 + d] = s * (1.f / (float)TT_);
}

// ---------------- decode head ----------------
__global__ __launch_bounds__(128) void head_k(const float* __restrict__ pooled,
                                              const float* __restrict__ toLW,
                                              const float* __restrict__ toLb,
                                              const float* __restrict__ dW1,
                                              const float* __restrict__ db1,
                                              const float* __restrict__ dW2,
                                              const float* __restrict__ db2,
                                              float* __restrict__ coeffs)
{
    const int b = blockIdx.x, j = threadIdx.x;
    __shared__ float hs[64];
    __shared__ float hid[128];
    float a = toLb[j];
    for (int d = 0; d < 256; ++d) a += pooled[b * 256 + d] * toLW[d * 128 + j];
    if (j < 64) hs[j] = a;
    __syncthreads();
    float a2 = db1[j];
    for (int z = 0; z < 64; ++z) a2 += hs[z] * dW1[z * 128 + j];
    hid[j] = fmaxf(a2, 0.f);
    __syncthreads();
    if (j < 120) {
        float a3 = db2[j];
        for (int k = 0; k < 128; ++k) a3 += hid[k] * dW2[k * 120 + j];
        coeffs[b * 120 + j] = a3;
    }
}

// ---------------- combined conv kernel ----------------
__global__ void comb_k(const float* __restrict__ selfK,
                       const float* __restrict__ cplW,
                       const float* __restrict__ cplB,
                       float* __restrict__ comb)
{
    const int n = threadIdx.x;
    for (int ti = 0; ti < 20; ++ti) {
        float s = selfK[ti * 256 + n];
        #pragma unroll
        for (int si = 0; si < 4; ++si) s += cplW[n * 4 + si] * cplB[ti * 4 + si];
        comb[n * 20 + ti] = s;
    }
}

// ---------------- final: 8 neurons per block, Y staged in LDS ----------------
__global__ __launch_bounds__(256) void final_k(const float* __restrict__ Y,
                                               const float* __restrict__ SB,
                                               const float* __restrict__ roW,
                                               const float* __restrict__ coeffs,
                                               const float* __restrict__ comb,
                                               float* __restrict__ out)
{
    const int b = blockIdx.x >> 5, nc = blockIdx.x & 31;
    const int n0 = nc * 8;
    const int tid = threadIdx.x;
    __shared__ float w[8][30], ck[8][20], yl[8][1020];
    if (tid < 240) {
        const int n = tid / 30, k = tid % 30;
        float s = 0.f;
        #pragma unroll
        for (int f = 0; f < 4; ++f)
            s += roW[(n0 + n) * 4 + f] * coeffs[b * 120 + f * 30 + k];
        w[n][k] = s;
    }
    if (tid < 160) {
        const int n = tid / 20, ta = tid % 20;
        ck[n][ta] = comb[(n0 + n) * 20 + ta];
    }
    #pragma unroll
    for (int n = 0; n < 8; ++n) {
        const float* yr = Y + ((size_t)(b * 256 + n0 + n)) * TTOT_ + 80;
        for (int j = tid; j < 1020; j += 256) yl[n][j] = yr[j];
    }
    __syncthreads();

    for (int t = tid; t < TT_; t += 256) {
        float sb[30];
        const float* sp = SB + (size_t)t * 30;
        #pragma unroll
        for (int k = 0; k < 30; ++k) sb[k] = sp[k];
        #pragma unroll
        for (int n = 0; n < 8; ++n) {
            float acc = 0.f;
            #pragma unroll
            for (int k = 0; k < 30; ++k) acc += w[n][k] * sb[k];
            #pragma unroll
            for (int tau = 1; tau <= 20; ++tau) acc += ck[n][tau - 1] * yl[n][t + 20 - tau];
            out[((size_t)(b * 256 + n0 + n)) * TT_ + t] = acc;
        }
    }
}

// ---------------- launch ----------------
extern "C" void kernel_launch(void* const* d_in, const int* in_sizes, int n_in,
                              void* d_out, int out_size, void* d_ws, size_t ws_size,
                              hipStream_t stream)
{
    const float* Y      = (const float*)d_in[0];
    const float* tokW   = (const float*)d_in[1];
    const float* tokb   = (const float*)d_in[2];
    const float* Wqkv   = (const float*)d_in[3];
    const float* bqkv   = (const float*)d_in[4];
    const float* Wo     = (const float*)d_in[5];
    const float* bo     = (const float*)d_in[6];
    const float* ln1g   = (const float*)d_in[7];
    const float* ln1b   = (const float*)d_in[8];
    const float* W1     = (const float*)d_in[9];
    const float* b1     = (const float*)d_in[10];
    const float* W2     = (const float*)d_in[11];
    const float* b2     = (const float*)d_in[12];
    const float* ln2g   = (const float*)d_in[13];
    const float* ln2b   = (const float*)d_in[14];
    const float* toLW   = (const float*)d_in[15];
    const float* toLb   = (const float*)d_in[16];
    const float* dW1    = (const float*)d_in[17];
    const float* db1    = (const float*)d_in[18];
    const float* dW2    = (const float*)d_in[19];
    const float* db2    = (const float*)d_in[20];
    const float* SB     = (const float*)d_in[21];
    const float* roW    = (const float*)d_in[22];
    const float* cplW   = (const float*)d_in[23];
    const float* cplB   = (const float*)d_in[24];
    const float* selfK  = (const float*)d_in[25];

    float* ws  = (float*)d_ws;
    float* X   = ws + X_OFF;
    short* Xb  = (short*)(ws + XB_OFF);
    short* O   = (short*)(ws + O_OFF);
    float* R   = ws + R_OFF;
    short* BIG = (short*)(ws + BIG_OFF);
    short* WT  = (short*)(ws + WT_OFF);
    float* PP  = ws + PP_OFF;
    float* PL  = ws + PL_OFF;
    float* CF  = ws + CF_OFF;
    float* CB  = ws + CB_OFF;

    short* WTqkv = WT;                 // 4 x 768x256
    short* WTo   = WT + 786432;        // 4 x 256x256
    short* WTw1  = WT + 1048576;       // 4 x 1024x256
    short* WTw2  = WT + 2097152;       // 4 x 256x1024

    wtr_k<<<dim3(24, 8, 4), 256, 0, stream>>>(Wqkv, WTqkv, 256, 768);
    wtr_k<<<dim3(8, 8, 4),  256, 0, stream>>>(Wo,   WTo,   256, 256);
    wtr_k<<<dim3(32, 8, 4), 256, 0, stream>>>(W1,   WTw1,  256, 1024);
    wtr_k<<<dim3(8, 32, 4), 256, 0, stream>>>(W2,   WTw2,  1024, 256);

    embed_k<<<dim3(250, 4), 256, 0, stream>>>(Y, tokW, tokb, X, Xb);

    for (int l = 0; l < 4; ++l) {
        bgemm_k<1, 0, 0><<<750, 256, 0, stream>>>(
            Xb, WTqkv + (size_t)l * 196608, bqkv + l * 768, nullptr, BIG,
            16000, 768, 256, 6);
        mattn_k<<<1024, 256, 0, stream>>>(BIG, O);
        bgemm_k<0, 0, 1><<<250, 256, 0, stream>>>(
            O, WTo + (size_t)l * 65536, bo + l * 256, X, R,
            16000, 256, 256, 2);
        ln_k<<<4000, 256, 0, stream>>>(R, ln1g + l * 256, ln1b + l * 256, X, Xb);
        bgemm_k<1, 1, 0><<<1000, 256, 0, stream>>>(
            Xb, WTw1 + (size_t)l * 262144, b1 + l * 1024, nullptr, BIG,
            16000, 1024, 256, 8);
        bgemm_k<0, 0, 1><<<250, 256, 0, stream>>>(
            BIG, WTw2 + (size_t)l * 262144, b2 + l * 256, X, R,
            16000, 256, 1024, 2);
        ln_k<<<4000, 256, 0, stream>>>(R, ln2g + l * 256, ln2b + l * 256, X, Xb);
    }

    pool_part_k<<<dim3(16, 8), 256, 0, stream>>>(X, PP);
    pool_red_k<<<16, 256, 0, stream>>>(PP, PL);
    head_k<<<16, 128, 0, stream>>>(PL, toLW, toLb, dW1, db1, dW2, db2, CF);
    comb_k<<<1, 256, 0, stream>>>(selfK, cplW, cplB, CB);
    final_k<<<512, 256, 0, stream>>>(Y, SB, roW, CF, CB, (float*)d_out);
}

// Round 5
// 667.396 us; speedup vs baseline: 5.0251x; 1.0116x over previous
//
#include <hip/hip_runtime.h>
#include <math.h>

// ---------------- problem constants ----------------
#define TT_   1000
#define TTOT_ 1100
#define NPAD_ 100
#define DD_   256
#define NN_   256

// workspace layout (float units)
#define X_OFF    0u           // fp32 residual stream 16000x256
#define XB_OFF   4096000u     // bf16 copy of X
#define O_OFF    6144000u     // bf16 attn out 16000x256
#define R_OFF    8192000u     // fp32 pre-LN buffer 16000x256
#define BIG_OFF  12288000u    // bf16 16000x1024 max
#define WT_OFF   20480000u    // bf16 transposed weights
#define PP_OFF   22052864u
#define PL_OFF   (PP_OFF + 32768u)
#define CF_OFF   (PL_OFF + 4096u)
#define CB_OFF   (CF_OFF + 1920u)

typedef __attribute__((ext_vector_type(8))) short s16x8;
typedef __attribute__((ext_vector_type(4))) float f32x4;
typedef __attribute__((ext_vector_type(16))) float f32x16;
typedef __attribute__((ext_vector_type(4))) unsigned u32x4;

__device__ inline short f2bf(float f) {
    unsigned u = __float_as_uint(f);
    u += 0x7fffu + ((u >> 16) & 1u);
    return (short)(u >> 16);
}

// async global->LDS, 16B per lane. LDS dest must be linear in lane order.
__device__ inline void gl_lds16(const short* g, short* l) {
    __builtin_amdgcn_global_load_lds(
        (const __attribute__((address_space(1))) void*)g,
        (__attribute__((address_space(3))) void*)l, 16, 0, 0);
}

// ---------------- weight transpose-convert ----------------
__global__ __launch_bounds__(256) void wtr_k(const float* __restrict__ in,
                                             short* __restrict__ out, int K, int N)
{
    __shared__ float t[32][33];
    const int n0 = blockIdx.x * 32, k0 = blockIdx.y * 32;
    in  += (size_t)blockIdx.z * K * N;
    out += (size_t)blockIdx.z * K * N;
    const int tx = threadIdx.x & 31, ty = threadIdx.x >> 5;
    #pragma unroll
    for (int i = 0; i < 4; ++i)
        t[ty + 8 * i][tx] = in[(size_t)(k0 + ty + 8 * i) * N + n0 + tx];
    __syncthreads();
    #pragma unroll
    for (int i = 0; i < 4; ++i)
        out[(size_t)(n0 + ty + 8 * i) * K + k0 + tx] = f2bf(t[tx][ty + 8 * i]);
}

// ---------------- bf16 MFMA GEMM (64x128 tile, 4 waves, m97 single-buffer) ----------------
// 24KB LDS -> ~6 blocks/CU; cross-block TLP hides the per-K-step vmcnt drain.
// A: MxK bf16 rm, Bt: NxK bf16 rm. M%64==0, N%128==0, K%64==0.
template<int OUTBF, int ACT, int RES>
__global__ __launch_bounds__(256) void bgemm_k(const short* __restrict__ A,
                                               const short* __restrict__ Bt,
                                               const float* __restrict__ bias,
                                               const float* __restrict__ resid,
                                               void* __restrict__ Cout,
                                               int M, int N, int K, int nby)
{
    __shared__ short As[64 * 64];
    __shared__ short Bs[128 * 64];
    const int tid = threadIdx.x;

    // bijective XCD swizzle; consecutive gids share the A panel (column-fast)
    const int nwg = gridDim.x;
    int gid = blockIdx.x;
    {
        const int q = nwg >> 3, r = nwg & 7;
        const int x = gid & 7, idx = gid >> 3;
        gid = (x < r ? x * (q + 1) : r * (q + 1) + (x - r) * q) + idx;
    }
    const int bx = gid / nby, by = gid - bx * nby;
    const int m0 = bx * 64, n0 = by * 128;

    const int wv = tid >> 6, lane = tid & 63;
    const int wr = wv >> 1, wc = wv & 1;
    const int l15 = lane & 15, lg = lane >> 4;

    f32x4 acc[2][4];
    #pragma unroll
    for (int i = 0; i < 2; ++i)
        #pragma unroll
        for (int j = 0; j < 4; ++j) acc[i][j] = (f32x4){0.f, 0.f, 0.f, 0.f};

    const int nt = K >> 6;
    for (int t = 0; t < nt; ++t) {
        __syncthreads();   // all waves done reading previous tile
        const int k0 = t << 6;
        #pragma unroll
        for (int i = 0; i < 2; ++i) {
            const int cid = i * 256 + tid;
            const int r = cid >> 3, c = cid & 7;
            gl_lds16(A + (size_t)(m0 + r) * K + k0 + ((c ^ (r & 7)) * 8), As + cid * 8);
        }
        #pragma unroll
        for (int i = 0; i < 4; ++i) {
            const int cid = i * 256 + tid;
            const int r = cid >> 3, c = cid & 7;
            gl_lds16(Bt + (size_t)(n0 + r) * K + k0 + ((c ^ (r & 7)) * 8), Bs + cid * 8);
        }
        __syncthreads();   // vmcnt(0) drain + barrier (compiler-emitted)

        #pragma unroll
        for (int ks = 0; ks < 2; ++ks) {
            s16x8 af[2], bf[4];
            #pragma unroll
            for (int mi = 0; mi < 2; ++mi) {
                const int row = wr * 32 + mi * 16 + l15;
                const int ch = ks * 4 + lg;
                af[mi] = *(const s16x8*)(As + row * 64 + ((ch ^ (row & 7)) * 8));
            }
            #pragma unroll
            for (int ni = 0; ni < 4; ++ni) {
                const int col = wc * 64 + ni * 16 + l15;
                const int ch = ks * 4 + lg;
                bf[ni] = *(const s16x8*)(Bs + col * 64 + ((ch ^ (col & 7)) * 8));
            }
            #pragma unroll
            for (int mi = 0; mi < 2; ++mi)
                #pragma unroll
                for (int ni = 0; ni < 4; ++ni)
                    acc[mi][ni] = __builtin_amdgcn_mfma_f32_16x16x32_bf16(
                        af[mi], bf[ni], acc[mi][ni], 0, 0, 0);
        }
    }

    #pragma unroll
    for (int mi = 0; mi < 2; ++mi) {
        #pragma unroll
        for (int ni = 0; ni < 4; ++ni) {
            const int col = n0 + wc * 64 + ni * 16 + l15;
            const float bv = bias[col];
            #pragma unroll
            for (int r = 0; r < 4; ++r) {
                const int row = m0 + wr * 32 + mi * 16 + lg * 4 + r;
                float v = acc[mi][ni][r] + bv;
                if (RES) v += resid[(size_t)row * N + col];
                if (ACT) v = 0.5f * v * (1.0f + erff(v * 0.70710678118654752f));
                if (OUTBF) ((short*)Cout)[(size_t)row * N + col] = f2bf(v);
                else       ((float*)Cout)[(size_t)row * N + col] = v;
            }
        }
    }
}

// ---------------- MFMA flash attention, swapped-QK^T 32x32 structure ----------------
// exp2-domain softmax (scale folded) + defer-max (THR = 8 nats = 11.54 in log2).
__global__ __launch_bounds__(256) void mattn_k(const short* __restrict__ qkv,
                                               short* __restrict__ o)
{
    int wg = blockIdx.x;
    wg = (wg & 7) * 128 + (wg >> 3);
    const int qt = wg & 7, h = (wg >> 3) & 7, b = wg >> 6;

    const int tid = threadIdx.x, wv = tid >> 6, lane = tid & 63;
    const int q31 = lane & 31, hi = lane >> 5;
    __shared__ short Ks[64 * 40];
    __shared__ short VT[32 * 72];

    const int q0w = qt * 128 + wv * 32;
    int qrow = q0w + q31; if (qrow > 999) qrow = 999;
    s16x8 bq[2];
    #pragma unroll
    for (int dh = 0; dh < 2; ++dh)
        bq[dh] = *(const s16x8*)(qkv + ((size_t)(b * TT_ + qrow)) * 768 + h * 32 + dh * 16 + hi * 8);

    f32x16 oacc;
    #pragma unroll
    for (int i = 0; i < 16; ++i) oacc[i] = 0.f;
    float mrun = -1e30f, lrun = 0.f;
    const float sc2 = 0.25503902254649546f;   // (1/sqrt(32)) * log2(e)

    for (int kt = 0; kt < 16; ++kt) {
        __syncthreads();
        {
            const int r = tid >> 2, c = tid & 3;
            int t = kt * 64 + r; if (t > 999) t = 999;
            const short* src = qkv + ((size_t)(b * TT_ + t)) * 768 + 256 + h * 32;
            s16x8 k8 = *(const s16x8*)(src + c * 8);
            *(s16x8*)(Ks + r * 40 + c * 8) = k8;
            s16x8 v8 = *(const s16x8*)(src + 256 + c * 8);
            #pragma unroll
            for (int j = 0; j < 8; ++j)
                VT[(c * 8 + j) * 72 + (((r >> 3) ^ c) * 8) + (r & 7)] = v8[j];
        }
        __syncthreads();

        f32x16 st[2];
        #pragma unroll
        for (int kb = 0; kb < 2; ++kb) {
            s16x8 kf0 = *(const s16x8*)(Ks + (kb * 32 + q31) * 40 + hi * 8);
            s16x8 kf1 = *(const s16x8*)(Ks + (kb * 32 + q31) * 40 + 16 + hi * 8);
            f32x16 z;
            #pragma unroll
            for (int i = 0; i < 16; ++i) z[i] = 0.f;
            z = __builtin_amdgcn_mfma_f32_32x32x16_bf16(kf0, bq[0], z, 0, 0, 0);
            z = __builtin_amdgcn_mfma_f32_32x32x16_bf16(kf1, bq[1], z, 0, 0, 0);
            st[kb] = z;
        }
        #pragma unroll
        for (int kb = 0; kb < 2; ++kb)
            #pragma unroll
            for (int r = 0; r < 16; ++r) st[kb][r] *= sc2;
        if (kt == 15) {
            #pragma unroll
            for (int kb = 0; kb < 2; ++kb)
                #pragma unroll
                for (int r = 0; r < 16; ++r) {
                    const int kloc = kb * 32 + (r & 3) + 8 * (r >> 2) + 4 * hi;
                    if (960 + kloc >= TT_) st[kb][r] = -1e30f;
                }
        }
        float mloc = st[0][0];
        #pragma unroll
        for (int kb = 0; kb < 2; ++kb)
            #pragma unroll
            for (int r = 0; r < 16; ++r) mloc = fmaxf(mloc, st[kb][r]);
        mloc = fmaxf(mloc, __shfl_xor(mloc, 32));
        // defer-max: skip rescale unless some row's max grew past THR (log2 dom.)
        if (!__all(mloc - mrun <= 11.54f)) {
            const float mn = fmaxf(mrun, mloc);
            const float alpha = exp2f(mrun - mn);
            mrun = mn;
            lrun *= alpha;
            #pragma unroll
            for (int i = 0; i < 16; ++i) oacc[i] *= alpha;
        }
        float sloc = 0.f;
        #pragma unroll
        for (int kb = 0; kb < 2; ++kb)
            #pragma unroll
            for (int r = 0; r < 16; ++r) {
                const float p = exp2f(st[kb][r] - mrun);
                st[kb][r] = p; sloc += p;
            }
        sloc += __shfl_xor(sloc, 32);
        lrun += sloc;

        unsigned wk[2][4][2];
        #pragma unroll
        for (int kb = 0; kb < 2; ++kb)
            #pragma unroll
            for (int a = 0; a < 4; ++a)
                #pragma unroll
                for (int h2 = 0; h2 < 2; ++h2) {
                    unsigned rr;
                    asm("v_cvt_pk_bf16_f32 %0, %1, %2"
                        : "=v"(rr)
                        : "v"(st[kb][4 * a + 2 * h2]), "v"(st[kb][4 * a + 2 * h2 + 1]));
                    wk[kb][a][h2] = rr;
                }

        #pragma unroll
        for (int ks = 0; ks < 4; ++ks) {
            const int kb = ks >> 1, qq = ks & 1;
            unsigned W[4];
            #pragma unroll
            for (int h2 = 0; h2 < 2; ++h2) {
                const unsigned send = hi ? wk[kb][2 * qq][h2] : wk[kb][2 * qq + 1][h2];
                const unsigned recv = __shfl_xor(send, 32);
                W[h2]     = hi ? recv : wk[kb][2 * qq][h2];
                W[2 + h2] = hi ? wk[kb][2 * qq + 1][h2] : recv;
            }
            u32x4 w4 = (u32x4){W[0], W[1], W[2], W[3]};
            s16x8 pb = __builtin_bit_cast(s16x8, w4);
            s16x8 vf = *(const s16x8*)(VT + q31 * 72 + (((2 * ks + hi) ^ (q31 >> 3)) * 8));
            oacc = __builtin_amdgcn_mfma_f32_32x32x16_bf16(vf, pb, oacc, 0, 0, 0);
        }
    }

    const int t = q0w + q31;
    if (t < TT_) {
        const float inv = 1.f / lrun;
        short* ob = o + ((size_t)(b * TT_ + t)) * 256 + h * 32;
        #pragma unroll
        for (int a = 0; a < 4; ++a) {
            const int d0 = 8 * a + 4 * hi;
            short4 s4;
            s4.x = f2bf(oacc[4 * a + 0] * inv);
            s4.y = f2bf(oacc[4 * a + 1] * inv);
            s4.z = f2bf(oacc[4 * a + 2] * inv);
            s4.w = f2bf(oacc[4 * a + 3] * inv);
            *(short4*)(ob + d0) = s4;
        }
    }
}

// ---------------- token embedding + positional encoding ----------------
__global__ __launch_bounds__(256) void embed_k(const float* __restrict__ Y,
                                               const float* __restrict__ W,
                                               const float* __restrict__ bias,
                                               float* __restrict__ X,
                                               short* __restrict__ Xb)
{
    __shared__ float As[16][68];
    __shared__ float Bs[16][68];
    const int tid = threadIdx.x;
    const int m0 = blockIdx.x * 64, n0 = blockIdx.y * 64;
    const int ty = tid >> 4, tx = tid & 15;
    const int la_m = tid >> 2, la_k = (tid & 3) * 4;
    const int lb_k = tid >> 4, lb_n = (tid & 15) * 4;

    const int rowA = m0 + la_m;
    const int bb = rowA / TT_, tt = rowA - bb * TT_;
    const float* yb = Y + (size_t)bb * NN_ * TTOT_ + NPAD_ + tt;

    float acc[4][4] = {};
    for (int k0 = 0; k0 < NN_; k0 += 16) {
        float a[4];
        #pragma unroll
        for (int j = 0; j < 4; ++j) a[j] = yb[(size_t)(k0 + la_k + j) * TTOT_];
        float4 b4 = *(const float4*)(W + (size_t)(k0 + lb_k) * DD_ + n0 + lb_n);
        __syncthreads();
        As[la_k + 0][la_m] = a[0]; As[la_k + 1][la_m] = a[1];
        As[la_k + 2][la_m] = a[2]; As[la_k + 3][la_m] = a[3];
        Bs[lb_k][lb_n + 0] = b4.x; Bs[lb_k][lb_n + 1] = b4.y;
        Bs[lb_k][lb_n + 2] = b4.z; Bs[lb_k][lb_n + 3] = b4.w;
        __syncthreads();
        #pragma unroll
        for (int k = 0; k < 16; ++k) {
            float ar[4], br[4];
            #pragma unroll
            for (int i = 0; i < 4; ++i) ar[i] = As[k][ty * 4 + i];
            #pragma unroll
            for (int j = 0; j < 4; ++j) br[j] = Bs[k][tx * 4 + j];
            #pragma unroll
            for (int i = 0; i < 4; ++i)
                #pragma unroll
                for (int j = 0; j < 4; ++j) acc[i][j] += ar[i] * br[j];
        }
    }
    #pragma unroll
    for (int i = 0; i < 4; ++i) {
        const int row = m0 + ty * 4 + i;
        const int t = row % TT_;
        #pragma unroll
        for (int j = 0; j < 4; ++j) {
            const int col = n0 + tx * 4 + j;
            float v = acc[i][j] + bias[col];
            const int i2 = col >> 1;
            const float div = expf(-(float)(2 * i2) * 0.0269834190585241f);
            const float ang = (float)t * div;
            v += (col & 1) ? cosf(ang) : sinf(ang);
            X[(size_t)row * DD_ + col] = v;
            Xb[(size_t)row * DD_ + col] = f2bf(v);
        }
    }
}

// ---------------- LayerNorm: 4 rows/block, 1 wave/row, float4 ----------------
__global__ __launch_bounds__(256) void ln_k(const float* __restrict__ in,
                                            const float* __restrict__ g,
                                            const float* __restrict__ b,
                                            float* __restrict__ out,
                                            short* __restrict__ outb)
{
    const int row = blockIdx.x * 4 + (threadIdx.x >> 6);
    const int lane = threadIdx.x & 63;
    const size_t base = (size_t)row * 256 + lane * 4;
    float4 v = *(const float4*)(in + base);
    float s = v.x + v.y + v.z + v.w;
    #pragma unroll
    for (int msk = 1; msk < 64; msk <<= 1) s += __shfl_xor(s, msk);
    const float mean = s * (1.f / 256.f);
    float4 d; d.x = v.x - mean; d.y = v.y - mean; d.z = v.z - mean; d.w = v.w - mean;
    float q = d.x * d.x + d.y * d.y + d.z * d.z + d.w * d.w;
    #pragma unroll
    for (int msk = 1; msk < 64; msk <<= 1) q += __shfl_xor(q, msk);
    const float rs = rsqrtf(q * (1.f / 256.f) + 1e-5f);
    const float4 g4 = *(const float4*)(g + lane * 4);
    const float4 b4 = *(const float4*)(b + lane * 4);
    float4 o4;
    o4.x = d.x * rs * g4.x + b4.x;
    o4.y = d.y * rs * g4.y + b4.y;
    o4.z = d.z * rs * g4.z + b4.z;
    o4.w = d.w * rs * g4.w + b4.w;
    *(float4*)(out + base) = o4;
    short4 s4;
    s4.x = f2bf(o4.x); s4.y = f2bf(o4.y); s4.z = f2bf(o4.z); s4.w = f2bf(o4.w);
    *(short4*)(outb + base) = s4;
}

// ---------------- mean pool ----------------
__global__ __launch_bounds__(256) void pool_part_k(const float* __restrict__ X,
                                                   float* __restrict__ partial)
{
    const int b = blockIdx.x, seg = blockIdx.y, d = threadIdx.x;
    float s = 0.f;
    const int t0 = seg * 125;
    for (int t = t0; t < t0 + 125; ++t) s += X[((size_t)b * TT_ + t) * 256 + d];
    partial[(b * 8 + seg) * 256 + d] = s;
}
__global__ __launch_bounds__(256) void pool_red_k(const float* __restrict__ partial,
                                                  float* __restrict__ pooled)
{
    const int b = blockIdx.x, d = threadIdx.x;
    float s = 0.f;
    for (int k = 0; k < 8; ++k) s += partial[(b * 8 + k) * 256 + d];
    pooled[b * 256 + d] = s * (1.f / (float)TT_);
}

// ---------------- decode head ----------------
__global__ __launch_bounds__(128) void head_k(const float* __restrict__ pooled,
                                              const float* __restrict__ toLW,
                                              const float* __restrict__ toLb,
                                              const float* __restrict__ dW1,
                                              const float* __restrict__ db1,
                                              const float* __restrict__ dW2,
                                              const float* __restrict__ db2,
                                              float* __restrict__ coeffs)
{
    const int b = blockIdx.x, j = threadIdx.x;
    __shared__ float hs[64];
    __shared__ float hid[128];
    float a = toLb[j];
    for (int d = 0; d < 256; ++d) a += pooled[b * 256 + d] * toLW[d * 128 + j];
    if (j < 64) hs[j] = a;
    __syncthreads();
    float a2 = db1[j];
    for (int z = 0; z < 64; ++z) a2 += hs[z] * dW1[z * 128 + j];
    hid[j] = fmaxf(a2, 0.f);
    __syncthreads();
    if (j < 120) {
        float a3 = db2[j];
        for (int k = 0; k < 128; ++k) a3 += hid[k] * dW2[k * 120 + j];
        coeffs[b * 120 + j] = a3;
    }
}

// ---------------- combined conv kernel ----------------
__global__ void comb_k(const float* __restrict__ selfK,
                       const float* __restrict__ cplW,
                       const float* __restrict__ cplB,
                       float* __restrict__ comb)
{
    const int n = threadIdx.x;
    for (int ti = 0; ti < 20; ++ti) {
        float s = selfK[ti * 256 + n];
        #pragma unroll
        for (int si = 0; si < 4; ++si) s += cplW[n * 4 + si] * cplB[ti * 4 + si];
        comb[n * 20 + ti] = s;
    }
}

// ---------------- final: 8 neurons per block, Y staged in LDS ----------------
__global__ __launch_bounds__(256) void final_k(const float* __restrict__ Y,
                                               const float* __restrict__ SB,
                                               const float* __restrict__ roW,
                                               const float* __restrict__ coeffs,
                                               const float* __restrict__ comb,
                                               float* __restrict__ out)
{
    const int b = blockIdx.x >> 5, nc = blockIdx.x & 31;
    const int n0 = nc * 8;
    const int tid = threadIdx.x;
    __shared__ float w[8][30], ck[8][20], yl[8][1020];
    if (tid < 240) {
        const int n = tid / 30, k = tid % 30;
        float s = 0.f;
        #pragma unroll
        for (int f = 0; f < 4; ++f)
            s += roW[(n0 + n) * 4 + f] * coeffs[b * 120 + f * 30 + k];
        w[n][k] = s;
    }
    if (tid < 160) {
        const int n = tid / 20, ta = tid % 20;
        ck[n][ta] = comb[(n0 + n) * 20 + ta];
    }
    #pragma unroll
    for (int n = 0; n < 8; ++n) {
        const float* yr = Y + ((size_t)(b * 256 + n0 + n)) * TTOT_ + 80;
        for (int j = tid; j < 1020; j += 256) yl[n][j] = yr[j];
    }
    __syncthreads();

    for (int t = tid; t < TT_; t += 256) {
        float sb[30];
        const float* sp = SB + (size_t)t * 30;
        #pragma unroll
        for (int k = 0; k < 30; ++k) sb[k] = sp[k];
        #pragma unroll
        for (int n = 0; n < 8; ++n) {
            float acc = 0.f;
            #pragma unroll
            for (int k = 0; k < 30; ++k) acc += w[n][k] * sb[k];
            #pragma unroll
            for (int tau = 1; tau <= 20; ++tau) acc += ck[n][tau - 1] * yl[n][t + 20 - tau];
            out[((size_t)(b * 256 + n0 + n)) * TT_ + t] = acc;
        }
    }
}

// ---------------- launch ----------------
extern "C" void kernel_launch(void* const* d_in, const int* in_sizes, int n_in,
                              void* d_out, int out_size, void* d_ws, size_t ws_size,
                              hipStream_t stream)
{
    const float* Y      = (const float*)d_in[0];
    const float* tokW   = (const float*)d_in[1];
    const float* tokb   = (const float*)d_in[2];
    const float* Wqkv   = (const float*)d_in[3];
    const float* bqkv   = (const float*)d_in[4];
    const float* Wo     = (const float*)d_in[5];
    const float* bo     = (const float*)d_in[6];
    const float* ln1g   = (const float*)d_in[7];
    const float* ln1b   = (const float*)d_in[8];
    const float* W1     = (const float*)d_in[9];
    const float* b1     = (const float*)d_in[10];
    const float* W2     = (const float*)d_in[11];
    const float* b2     = (const float*)d_in[12];
    const float* ln2g   = (const float*)d_in[13];
    const float* ln2b   = (const float*)d_in[14];
    const float* toLW   = (const float*)d_in[15];
    const float* toLb   = (const float*)d_in[16];
    const float* dW1    = (const float*)d_in[17];
    const float* db1    = (const float*)d_in[18];
    const float* dW2    = (const float*)d_in[19];
    const float* db2    = (const float*)d_in[20];
    const float* SB     = (const float*)d_in[21];
    const float* roW    = (const float*)d_in[22];
    const float* cplW   = (const float*)d_in[23];
    const float* cplB   = (const float*)d_in[24];
    const float* selfK  = (const float*)d_in[25];

    float* ws  = (float*)d_ws;
    float* X   = ws + X_OFF;
    short* Xb  = (short*)(ws + XB_OFF);
    short* O   = (short*)(ws + O_OFF);
    float* R   = ws + R_OFF;
    short* BIG = (short*)(ws + BIG_OFF);
    short* WT  = (short*)(ws + WT_OFF);
    float* PP  = ws + PP_OFF;
    float* PL  = ws + PL_OFF;
    float* CF  = ws + CF_OFF;
    float* CB  = ws + CB_OFF;

    short* WTqkv = WT;                 // 4 x 768x256
    short* WTo   = WT + 786432;        // 4 x 256x256
    short* WTw1  = WT + 1048576;       // 4 x 1024x256
    short* WTw2  = WT + 2097152;       // 4 x 256x1024

    wtr_k<<<dim3(24, 8, 4), 256, 0, stream>>>(Wqkv, WTqkv, 256, 768);
    wtr_k<<<dim3(8, 8, 4),  256, 0, stream>>>(Wo,   WTo,   256, 256);
    wtr_k<<<dim3(32, 8, 4), 256, 0, stream>>>(W1,   WTw1,  256, 1024);
    wtr_k<<<dim3(8, 32, 4), 256, 0, stream>>>(W2,   WTw2,  1024, 256);

    embed_k<<<dim3(250, 4), 256, 0, stream>>>(Y, tokW, tokb, X, Xb);

    for (int l = 0; l < 4; ++l) {
        bgemm_k<1, 0, 0><<<1500, 256, 0, stream>>>(
            Xb, WTqkv + (size_t)l * 196608, bqkv + l * 768, nullptr, BIG,
            16000, 768, 256, 6);
        mattn_k<<<1024, 256, 0, stream>>>(BIG, O);
        bgemm_k<0, 0, 1><<<500, 256, 0, stream>>>(
            O, WTo + (size_t)l * 65536, bo + l * 256, X, R,
            16000, 256, 256, 2);
        ln_k<<<4000, 256, 0, stream>>>(R, ln1g + l * 256, ln1b + l * 256, X, Xb);
        bgemm_k<1, 1, 0><<<2000, 256, 0, stream>>>(
            Xb, WTw1 + (size_t)l * 262144, b1 + l * 1024, nullptr, BIG,
            16000, 1024, 256, 8);
        bgemm_k<0, 0, 1><<<500, 256, 0, stream>>>(
            BIG, WTw2 + (size_t)l * 262144, b2 + l * 256, X, R,
            16000, 256, 1024, 2);
        ln_k<<<4000, 256, 0, stream>>>(R, ln2g + l * 256, ln2b + l * 256, X, Xb);
    }

    pool_part_k<<<dim3(16, 8), 256, 0, stream>>>(X, PP);
    pool_red_k<<<16, 256, 0, stream>>>(PP, PL);
    head_k<<<16, 128, 0, stream>>>(PL, toLW, toLb, dW1, db1, dW2, db2, CF);
    comb_k<<<1, 256, 0, stream>>>(selfK, cplW, cplB, CB);
    final_k<<<512, 256, 0, stream>>>(Y, SB, roW, CF, CB, (float*)d_out);
}

// Round 6
// 585.469 us; speedup vs baseline: 5.7283x; 1.1399x over previous
//
#include <hip/hip_runtime.h>
#include <math.h>

// ---------------- problem constants ----------------
#define TT_   1000
#define TTOT_ 1100
#define NPAD_ 100
#define DD_   256
#define NN_   256

// workspace layout (float units)
#define X_OFF    0u           // fp32 residual 16000x256
#define XB_OFF   4096000u     // bf16 X
#define O_OFF    6144000u     // bf16 attn out
#define R_OFF    8192000u     // fp32 pre-LN
#define BIG_OFF  12288000u    // bf16 16000x1024 max (also Ybt before qkv)
#define WT_OFF   20480000u    // bf16 weights: qkv|o|w1|w2|tok = 3211264 shorts
#define PE_OFF   22085632u    // fp32 pos-enc 1000x256
#define PP_OFF   22341632u
#define PL_OFF   (PP_OFF + 32768u)
#define CF_OFF   (PL_OFF + 4096u)
#define CB_OFF   (CF_OFF + 1920u)
#define BQ_OFF   (CB_OFF + 5120u)   // scaled bqkv 4x768

#define SC2_ 0.25503902254649546f   // (1/sqrt(32)) * log2(e)

typedef __attribute__((ext_vector_type(8))) short s16x8;
typedef __attribute__((ext_vector_type(4))) float f32x4;
typedef __attribute__((ext_vector_type(16))) float f32x16;
typedef __attribute__((ext_vector_type(4))) unsigned u32x4;

__device__ inline short f2bf(float f) {
    unsigned u = __float_as_uint(f);
    u += 0x7fffu + ((u >> 16) & 1u);
    return (short)(u >> 16);
}
__device__ inline float exp2i(float x) {   // native 2^x
    float r; asm("v_exp_f32 %0, %1" : "=v"(r) : "v"(x)); return r;
}

// async global->LDS, 16B per lane; LDS dest linear in lane order.
__device__ inline void gl_lds16(const short* g, short* l) {
    __builtin_amdgcn_global_load_lds(
        (const __attribute__((address_space(1))) void*)g,
        (__attribute__((address_space(3))) void*)l, 16, 0, 0);
}

// ---------------- weight transpose-convert (rows < qrows scaled by qs) ----------------
__global__ __launch_bounds__(256) void wtr_k(const float* __restrict__ in,
                                             short* __restrict__ out, int K, int N,
                                             int qrows, float qs)
{
    __shared__ float t[32][33];
    const int n0 = blockIdx.x * 32, k0 = blockIdx.y * 32;
    in  += (size_t)blockIdx.z * K * N;
    out += (size_t)blockIdx.z * K * N;
    const int tx = threadIdx.x & 31, ty = threadIdx.x >> 5;
    #pragma unroll
    for (int i = 0; i < 4; ++i)
        t[ty + 8 * i][tx] = in[(size_t)(k0 + ty + 8 * i) * N + n0 + tx];
    __syncthreads();
    #pragma unroll
    for (int i = 0; i < 4; ++i) {
        const int row = n0 + ty + 8 * i;
        float f = t[tx][ty + 8 * i];
        if (row < qrows) f *= qs;
        out[(size_t)row * K + k0 + tx] = f2bf(f);
    }
}

// ---------------- Y transpose-convert: Ybt[(b*1000+t)][n] = bf16(Y[b][n][100+t]) ----------------
__global__ __launch_bounds__(256) void ytr_k(const float* __restrict__ Y,
                                             short* __restrict__ out)
{
    __shared__ float t[32][33];
    const int b = blockIdx.z;
    const int t0 = blockIdx.x * 32, n0 = blockIdx.y * 32;
    const int tx = threadIdx.x & 31, ty = threadIdx.x >> 5;
    #pragma unroll
    for (int i = 0; i < 4; ++i) {
        const int tt = t0 + tx;
        t[ty + 8 * i][tx] = (tt < TT_)
            ? Y[((size_t)(b * NN_ + n0 + ty + 8 * i)) * TTOT_ + NPAD_ + tt] : 0.f;
    }
    __syncthreads();
    #pragma unroll
    for (int i = 0; i < 4; ++i) {
        const int tt = t0 + ty + 8 * i;
        if (tt < TT_)
            out[((size_t)(b * TT_ + tt)) * NN_ + n0 + tx] = f2bf(t[tx][ty + 8 * i]);
    }
}

// ---------------- positional-encoding table ----------------
__global__ void pe_k(float* __restrict__ PE)
{
    const int t = blockIdx.x, d = threadIdx.x;
    const float div = __expf(-(float)(d & ~1) * 0.0269834190585241f); // ln(1000)/256
    const float ang = (float)t * div;
    PE[t * 256 + d] = (d & 1) ? cosf(ang) : sinf(ang);
}

// ---------------- scaled bias copy (qkv: cols<256 scaled) ----------------
__global__ void bscale_k(const float* __restrict__ in, float* __restrict__ out)
{
    const int i = blockIdx.x * 256 + threadIdx.x;
    if (i < 3072) {
        const int col = i % 768;
        out[i] = in[i] * ((col < 256) ? SC2_ : 1.f);
    }
}

// ---------------- bf16 MFMA GEMM (64x128 tile, 4 waves, single-buffer) ----------------
// RES: 0=none, 1=resid[row][col], 2=resid[(row%1000)][col] (PE). DUAL: also write bf16 Cb.
template<int OUTBF, int ACT, int RES, int DUAL>
__global__ __launch_bounds__(256) void bgemm_k(const short* __restrict__ A,
                                               const short* __restrict__ Bt,
                                               const float* __restrict__ bias,
                                               const float* __restrict__ resid,
                                               void* __restrict__ Cout,
                                               short* __restrict__ Cb,
                                               int M, int N, int K, int nby)
{
    __shared__ short As[64 * 64];
    __shared__ short Bs[128 * 64];
    const int tid = threadIdx.x;

    const int nwg = gridDim.x;
    int gid = blockIdx.x;
    {
        const int q = nwg >> 3, r = nwg & 7;
        const int x = gid & 7, idx = gid >> 3;
        gid = (x < r ? x * (q + 1) : r * (q + 1) + (x - r) * q) + idx;
    }
    const int bx = gid / nby, by = gid - bx * nby;
    const int m0 = bx * 64, n0 = by * 128;

    const int wv = tid >> 6, lane = tid & 63;
    const int wr = wv >> 1, wc = wv & 1;
    const int l15 = lane & 15, lg = lane >> 4;

    f32x4 acc[2][4];
    #pragma unroll
    for (int i = 0; i < 2; ++i)
        #pragma unroll
        for (int j = 0; j < 4; ++j) acc[i][j] = (f32x4){0.f, 0.f, 0.f, 0.f};

    const int nt = K >> 6;
    for (int t = 0; t < nt; ++t) {
        __syncthreads();
        const int k0 = t << 6;
        #pragma unroll
        for (int i = 0; i < 2; ++i) {
            const int cid = i * 256 + tid;
            const int r = cid >> 3, c = cid & 7;
            gl_lds16(A + (size_t)(m0 + r) * K + k0 + ((c ^ (r & 7)) * 8), As + cid * 8);
        }
        #pragma unroll
        for (int i = 0; i < 4; ++i) {
            const int cid = i * 256 + tid;
            const int r = cid >> 3, c = cid & 7;
            gl_lds16(Bt + (size_t)(n0 + r) * K + k0 + ((c ^ (r & 7)) * 8), Bs + cid * 8);
        }
        __syncthreads();

        #pragma unroll
        for (int ks = 0; ks < 2; ++ks) {
            s16x8 af[2], bf[4];
            #pragma unroll
            for (int mi = 0; mi < 2; ++mi) {
                const int row = wr * 32 + mi * 16 + l15;
                const int ch = ks * 4 + lg;
                af[mi] = *(const s16x8*)(As + row * 64 + ((ch ^ (row & 7)) * 8));
            }
            #pragma unroll
            for (int ni = 0; ni < 4; ++ni) {
                const int col = wc * 64 + ni * 16 + l15;
                const int ch = ks * 4 + lg;
                bf[ni] = *(const s16x8*)(Bs + col * 64 + ((ch ^ (col & 7)) * 8));
            }
            #pragma unroll
            for (int mi = 0; mi < 2; ++mi)
                #pragma unroll
                for (int ni = 0; ni < 4; ++ni)
                    acc[mi][ni] = __builtin_amdgcn_mfma_f32_16x16x32_bf16(
                        af[mi], bf[ni], acc[mi][ni], 0, 0, 0);
        }
    }

    #pragma unroll
    for (int mi = 0; mi < 2; ++mi) {
        #pragma unroll
        for (int ni = 0; ni < 4; ++ni) {
            const int col = n0 + wc * 64 + ni * 16 + l15;
            const float bv = bias[col];
            #pragma unroll
            for (int r = 0; r < 4; ++r) {
                const int row = m0 + wr * 32 + mi * 16 + lg * 4 + r;
                float v = acc[mi][ni][r] + bv;
                if (RES == 1) v += resid[(size_t)row * N + col];
                if (RES == 2) v += resid[(size_t)(row % 1000) * N + col];
                if (ACT) v = 0.5f * v * (1.0f + erff(v * 0.70710678118654752f));
                if (OUTBF) ((short*)Cout)[(size_t)row * N + col] = f2bf(v);
                else       ((float*)Cout)[(size_t)row * N + col] = v;
                if (DUAL)  Cb[(size_t)row * N + col] = f2bf(v);
            }
        }
    }
}

// ---------------- MFMA flash attention: swapped QK^T, no-max softmax ----------------
// Scores pre-scaled into Q (W_q folded with sc*log2e): p = 2^s directly.
// Double-buffered K/V, async-stage split, 1 barrier/tile.
__global__ __launch_bounds__(256) void mattn_k(const short* __restrict__ qkv,
                                               short* __restrict__ o)
{
    int wg = blockIdx.x;
    wg = (wg & 7) * 128 + (wg >> 3);
    const int qt = wg & 7, h = (wg >> 3) & 7, b = wg >> 6;

    const int tid = threadIdx.x, wv = tid >> 6, lane = tid & 63;
    const int q31 = lane & 31, hi = lane >> 5;
    __shared__ short Ks[2][64 * 40];
    __shared__ short VT[2][32 * 72];

    const int q0w = qt * 128 + wv * 32;
    int qrow = q0w + q31; if (qrow > 999) qrow = 999;
    s16x8 bq[2];
    #pragma unroll
    for (int dh = 0; dh < 2; ++dh)
        bq[dh] = *(const s16x8*)(qkv + ((size_t)(b * TT_ + qrow)) * 768 + h * 32 + dh * 16 + hi * 8);

    f32x16 oacc;
    #pragma unroll
    for (int i = 0; i < 16; ++i) oacc[i] = 0.f;
    float lrun = 0.f;

    const int sr = tid >> 2, sc = tid & 3;
    s16x8 kreg, vreg;
    auto LOADT = [&](int kt) {
        int t = kt * 64 + sr; if (t > 999) t = 999;
        const short* src = qkv + ((size_t)(b * TT_ + t)) * 768 + 256 + h * 32;
        kreg = *(const s16x8*)(src + sc * 8);
        vreg = *(const s16x8*)(src + 256 + sc * 8);
    };
    auto WRITET = [&](int buf) {
        *(s16x8*)(&Ks[buf][sr * 40 + sc * 8]) = kreg;
        #pragma unroll
        for (int j = 0; j < 8; ++j)
            VT[buf][(sc * 8 + j) * 72 + (((sr >> 3) ^ sc) * 8) + (sr & 7)] = vreg[j];
    };

    LOADT(0); WRITET(0);
    __syncthreads();
    int cur = 0;

    for (int kt = 0; kt < 16; ++kt) {
        if (kt < 15) LOADT(kt + 1);     // in flight under compute

        // S^T[k][q] (already includes softmax scale & log2e via W_q fold)
        f32x16 st[2];
        __builtin_amdgcn_s_setprio(1);
        #pragma unroll
        for (int kb = 0; kb < 2; ++kb) {
            s16x8 kf0 = *(const s16x8*)(&Ks[cur][(kb * 32 + q31) * 40 + hi * 8]);
            s16x8 kf1 = *(const s16x8*)(&Ks[cur][(kb * 32 + q31) * 40 + 16 + hi * 8]);
            f32x16 z;
            #pragma unroll
            for (int i = 0; i < 16; ++i) z[i] = 0.f;
            z = __builtin_amdgcn_mfma_f32_32x32x16_bf16(kf0, bq[0], z, 0, 0, 0);
            z = __builtin_amdgcn_mfma_f32_32x32x16_bf16(kf1, bq[1], z, 0, 0, 0);
            st[kb] = z;
        }
        __builtin_amdgcn_s_setprio(0);

        if (kt == 15) {   // mask tail keys >= 1000
            #pragma unroll
            for (int kb = 0; kb < 2; ++kb)
                #pragma unroll
                for (int r = 0; r < 16; ++r) {
                    const int kloc = kb * 32 + (r & 3) + 8 * (r >> 2) + 4 * hi;
                    if (960 + kloc >= TT_) st[kb][r] = -1e30f;
                }
        }

        float sloc = 0.f;
        #pragma unroll
        for (int kb = 0; kb < 2; ++kb)
            #pragma unroll
            for (int r = 0; r < 16; ++r) {
                const float p = exp2i(st[kb][r]);
                st[kb][r] = p; sloc += p;
            }
        sloc += __shfl_xor(sloc, 32);
        lrun += sloc;

        // pack P to bf16: wk[kb][a][h2] covers k2 = kb*32 + 8a + 4hi + 2h2
        unsigned wk[2][4][2];
        #pragma unroll
        for (int kb = 0; kb < 2; ++kb)
            #pragma unroll
            for (int a = 0; a < 4; ++a)
                #pragma unroll
                for (int h2 = 0; h2 < 2; ++h2) {
                    unsigned rr;
                    asm("v_cvt_pk_bf16_f32 %0, %1, %2"
                        : "=v"(rr)
                        : "v"(st[kb][4 * a + 2 * h2]), "v"(st[kb][4 * a + 2 * h2 + 1]));
                    wk[kb][a][h2] = rr;
                }

        // PV: O^T += V^T · P
        #pragma unroll
        for (int ks = 0; ks < 4; ++ks) {
            const int kb = ks >> 1, qq = ks & 1;
            unsigned W[4];
            #pragma unroll
            for (int h2 = 0; h2 < 2; ++h2) {
                const unsigned send = hi ? wk[kb][2 * qq][h2] : wk[kb][2 * qq + 1][h2];
                const unsigned recv = __shfl_xor(send, 32);
                W[h2]     = hi ? recv : wk[kb][2 * qq][h2];
                W[2 + h2] = hi ? wk[kb][2 * qq + 1][h2] : recv;
            }
            u32x4 w4 = (u32x4){W[0], W[1], W[2], W[3]};
            s16x8 pb = __builtin_bit_cast(s16x8, w4);
            s16x8 vf = *(const s16x8*)(&VT[cur][q31 * 72 + (((2 * ks + hi) ^ (q31 >> 3)) * 8)]);
            __builtin_amdgcn_s_setprio(1);
            oacc = __builtin_amdgcn_mfma_f32_32x32x16_bf16(vf, pb, oacc, 0, 0, 0);
            __builtin_amdgcn_s_setprio(0);
        }

        if (kt < 15) WRITET(cur ^ 1);   // land next tile after compute
        __syncthreads();
        cur ^= 1;
    }

    const int t = q0w + q31;
    if (t < TT_) {
        const float inv = 1.f / lrun;
        short* ob = o + ((size_t)(b * TT_ + t)) * 256 + h * 32;
        #pragma unroll
        for (int a = 0; a < 4; ++a) {
            unsigned w0, w1;
            asm("v_cvt_pk_bf16_f32 %0, %1, %2"
                : "=v"(w0) : "v"(oacc[4 * a + 0] * inv), "v"(oacc[4 * a + 1] * inv));
            asm("v_cvt_pk_bf16_f32 %0, %1, %2"
                : "=v"(w1) : "v"(oacc[4 * a + 2] * inv), "v"(oacc[4 * a + 3] * inv));
            const int d0 = 8 * a + 4 * hi;
            *(unsigned*)(ob + d0) = w0;
            *(unsigned*)(ob + d0 + 2) = w1;
        }
    }
}

// ---------------- LayerNorm: 4 rows/block, 1 wave/row, float4 ----------------
__global__ __launch_bounds__(256) void ln_k(const float* __restrict__ in,
                                            const float* __restrict__ g,
                                            const float* __restrict__ b,
                                            float* __restrict__ out,
                                            short* __restrict__ outb)
{
    const int row = blockIdx.x * 4 + (threadIdx.x >> 6);
    const int lane = threadIdx.x & 63;
    const size_t base = (size_t)row * 256 + lane * 4;
    float4 v = *(const float4*)(in + base);
    float s = v.x + v.y + v.z + v.w;
    #pragma unroll
    for (int msk = 1; msk < 64; msk <<= 1) s += __shfl_xor(s, msk);
    const float mean = s * (1.f / 256.f);
    float4 d; d.x = v.x - mean; d.y = v.y - mean; d.z = v.z - mean; d.w = v.w - mean;
    float q = d.x * d.x + d.y * d.y + d.z * d.z + d.w * d.w;
    #pragma unroll
    for (int msk = 1; msk < 64; msk <<= 1) q += __shfl_xor(q, msk);
    const float rs = rsqrtf(q * (1.f / 256.f) + 1e-5f);
    const float4 g4 = *(const float4*)(g + lane * 4);
    const float4 b4 = *(const float4*)(b + lane * 4);
    float4 o4;
    o4.x = d.x * rs * g4.x + b4.x;
    o4.y = d.y * rs * g4.y + b4.y;
    o4.z = d.z * rs * g4.z + b4.z;
    o4.w = d.w * rs * g4.w + b4.w;
    *(float4*)(out + base) = o4;
    short4 s4;
    s4.x = f2bf(o4.x); s4.y = f2bf(o4.y); s4.z = f2bf(o4.z); s4.w = f2bf(o4.w);
    *(short4*)(outb + base) = s4;
}

// ---------------- mean pool ----------------
__global__ __launch_bounds__(256) void pool_part_k(const float* __restrict__ X,
                                                   float* __restrict__ partial)
{
    const int b = blockIdx.x, seg = blockIdx.y, d = threadIdx.x;
    float s = 0.f;
    const int t0 = seg * 125;
    for (int t = t0; t < t0 + 125; ++t) s += X[((size_t)b * TT_ + t) * 256 + d];
    partial[(b * 8 + seg) * 256 + d] = s;
}
__global__ __launch_bounds__(256) void pool_red_k(const float* __restrict__ partial,
                                                  float* __restrict__ pooled)
{
    const int b = blockIdx.x, d = threadIdx.x;
    float s = 0.f;
    for (int k = 0; k < 8; ++k) s += partial[(b * 8 + k) * 256 + d];
    pooled[b * 256 + d] = s * (1.f / (float)TT_);
}

// ---------------- decode head ----------------
__global__ __launch_bounds__(128) void head_k(const float* __restrict__ pooled,
                                              const float* __restrict__ toLW,
                                              const float* __restrict__ toLb,
                                              const float* __restrict__ dW1,
                                              const float* __restrict__ db1,
                                              const float* __restrict__ dW2,
                                              const float* __restrict__ db2,
                                              float* __restrict__ coeffs)
{
    const int b = blockIdx.x, j = threadIdx.x;
    __shared__ float hs[64];
    __shared__ float hid[128];
    float a = toLb[j];
    for (int d = 0; d < 256; ++d) a += pooled[b * 256 + d] * toLW[d * 128 + j];
    if (j < 64) hs[j] = a;
    __syncthreads();
    float a2 = db1[j];
    for (int z = 0; z < 64; ++z) a2 += hs[z] * dW1[z * 128 + j];
    hid[j] = fmaxf(a2, 0.f);
    __syncthreads();
    if (j < 120) {
        float a3 = db2[j];
        for (int k = 0; k < 128; ++k) a3 += hid[k] * dW2[k * 120 + j];
        coeffs[b * 120 + j] = a3;
    }
}

// ---------------- combined conv kernel ----------------
__global__ void comb_k(const float* __restrict__ selfK,
                       const float* __restrict__ cplW,
                       const float* __restrict__ cplB,
                       float* __restrict__ comb)
{
    const int n = threadIdx.x;
    for (int ti = 0; ti < 20; ++ti) {
        float s = selfK[ti * 256 + n];
        #pragma unroll
        for (int si = 0; si < 4; ++si) s += cplW[n * 4 + si] * cplB[ti * 4 + si];
        comb[n * 20 + ti] = s;
    }
}

// ---------------- final: 8 neurons per block, Y staged in LDS ----------------
__global__ __launch_bounds__(256) void final_k(const float* __restrict__ Y,
                                               const float* __restrict__ SB,
                                               const float* __restrict__ roW,
                                               const float* __restrict__ coeffs,
                                               const float* __restrict__ comb,
                                               float* __restrict__ out)
{
    const int b = blockIdx.x >> 5, nc = blockIdx.x & 31;
    const int n0 = nc * 8;
    const int tid = threadIdx.x;
    __shared__ float w[8][30], ck[8][20], yl[8][1020];
    if (tid < 240) {
        const int n = tid / 30, k = tid % 30;
        float s = 0.f;
        #pragma unroll
        for (int f = 0; f < 4; ++f)
            s += roW[(n0 + n) * 4 + f] * coeffs[b * 120 + f * 30 + k];
        w[n][k] = s;
    }
    if (tid < 160) {
        const int n = tid / 20, ta = tid % 20;
        ck[n][ta] = comb[(n0 + n) * 20 + ta];
    }
    #pragma unroll
    for (int n = 0; n < 8; ++n) {
        const float* yr = Y + ((size_t)(b * 256 + n0 + n)) * TTOT_ + 80;
        for (int j = tid; j < 1020; j += 256) yl[n][j] = yr[j];
    }
    __syncthreads();

    for (int t = tid; t < TT_; t += 256) {
        float sb[30];
        const float* sp = SB + (size_t)t * 30;
        #pragma unroll
        for (int k = 0; k < 30; ++k) sb[k] = sp[k];
        #pragma unroll
        for (int n = 0; n < 8; ++n) {
            float acc = 0.f;
            #pragma unroll
            for (int k = 0; k < 30; ++k) acc += w[n][k] * sb[k];
            #pragma unroll
            for (int tau = 1; tau <= 20; ++tau) acc += ck[n][tau - 1] * yl[n][t + 20 - tau];
            out[((size_t)(b * 256 + n0 + n)) * TT_ + t] = acc;
        }
    }
}

// ---------------- launch ----------------
extern "C" void kernel_launch(void* const* d_in, const int* in_sizes, int n_in,
                              void* d_out, int out_size, void* d_ws, size_t ws_size,
                              hipStream_t stream)
{
    const float* Y      = (const float*)d_in[0];
    const float* tokW   = (const float*)d_in[1];
    const float* tokb   = (const float*)d_in[2];
    const float* Wqkv   = (const float*)d_in[3];
    const float* bqkv   = (const float*)d_in[4];
    const float* Wo     = (const float*)d_in[5];
    const float* bo     = (const float*)d_in[6];
    const float* ln1g   = (const float*)d_in[7];
    const float* ln1b   = (const float*)d_in[8];
    const float* W1     = (const float*)d_in[9];
    const float* b1     = (const float*)d_in[10];
    const float* W2     = (const float*)d_in[11];
    const float* b2     = (const float*)d_in[12];
    const float* ln2g   = (const float*)d_in[13];
    const float* ln2b   = (const float*)d_in[14];
    const float* toLW   = (const float*)d_in[15];
    const float* toLb   = (const float*)d_in[16];
    const float* dW1    = (const float*)d_in[17];
    const float* db1    = (const float*)d_in[18];
    const float* dW2    = (const float*)d_in[19];
    const float* db2    = (const float*)d_in[20];
    const float* SB     = (const float*)d_in[21];
    const float* roW    = (const float*)d_in[22];
    const float* cplW   = (const float*)d_in[23];
    const float* cplB   = (const float*)d_in[24];
    const float* selfK  = (const float*)d_in[25];

    float* ws  = (float*)d_ws;
    float* X   = ws + X_OFF;
    short* Xb  = (short*)(ws + XB_OFF);
    short* O   = (short*)(ws + O_OFF);
    float* R   = ws + R_OFF;
    short* BIG = (short*)(ws + BIG_OFF);
    short* WT  = (short*)(ws + WT_OFF);
    float* PE  = ws + PE_OFF;
    float* PP  = ws + PP_OFF;
    float* PL  = ws + PL_OFF;
    float* CF  = ws + CF_OFF;
    float* CB  = ws + CB_OFF;
    float* BQ  = ws + BQ_OFF;

    short* WTqkv = WT;                 // 4 x 768x256 (Q rows pre-scaled)
    short* WTo   = WT + 786432;        // 4 x 256x256
    short* WTw1  = WT + 1048576;       // 4 x 1024x256
    short* WTw2  = WT + 2097152;       // 4 x 256x1024
    short* WTtok = WT + 3145728;       // 256x256
    short* Ybt   = BIG;                // 16000x256 bf16 (freed before qkv use)

    wtr_k<<<dim3(24, 8, 4), 256, 0, stream>>>(Wqkv, WTqkv, 256, 768, 256, SC2_);
    wtr_k<<<dim3(8, 8, 4),  256, 0, stream>>>(Wo,   WTo,   256, 256, 0, 1.f);
    wtr_k<<<dim3(32, 8, 4), 256, 0, stream>>>(W1,   WTw1,  256, 1024, 0, 1.f);
    wtr_k<<<dim3(8, 32, 4), 256, 0, stream>>>(W2,   WTw2,  1024, 256, 0, 1.f);
    wtr_k<<<dim3(8, 8, 1),  256, 0, stream>>>(tokW, WTtok, 256, 256, 0, 1.f);
    bscale_k<<<12, 256, 0, stream>>>(bqkv, BQ);
    pe_k<<<1000, 256, 0, stream>>>(PE);
    ytr_k<<<dim3(32, 8, 16), 256, 0, stream>>>(Y, Ybt);

    // embed: X = Ybt @ tokW + tokb + PE  (fp32 + bf16 out)
    bgemm_k<0, 0, 2, 1><<<500, 256, 0, stream>>>(
        Ybt, WTtok, tokb, PE, X, Xb, 16000, 256, 256, 2);

    for (int l = 0; l < 4; ++l) {
        bgemm_k<1, 0, 0, 0><<<1500, 256, 0, stream>>>(
            Xb, WTqkv + (size_t)l * 196608, BQ + l * 768, nullptr, BIG, nullptr,
            16000, 768, 256, 6);
        mattn_k<<<1024, 256, 0, stream>>>(BIG, O);
        bgemm_k<0, 0, 1, 0><<<500, 256, 0, stream>>>(
            O, WTo + (size_t)l * 65536, bo + l * 256, X, R, nullptr,
            16000, 256, 256, 2);
        ln_k<<<4000, 256, 0, stream>>>(R, ln1g + l * 256, ln1b + l * 256, X, Xb);
        bgemm_k<1, 1, 0, 0><<<2000, 256, 0, stream>>>(
            Xb, WTw1 + (size_t)l * 262144, b1 + l * 1024, nullptr, BIG, nullptr,
            16000, 1024, 256, 8);
        bgemm_k<0, 0, 1, 0><<<500, 256, 0, stream>>>(
            BIG, WTw2 + (size_t)l * 262144, b2 + l * 256, X, R, nullptr,
            16000, 256, 1024, 2);
        ln_k<<<4000, 256, 0, stream>>>(R, ln2g + l * 256, ln2b + l * 256, X, Xb);
    }

    pool_part_k<<<dim3(16, 8), 256, 0, stream>>>(X, PP);
    pool_red_k<<<16, 256, 0, stream>>>(PP, PL);
    head_k<<<16, 128, 0, stream>>>(PL, toLW, toLb, dW1, db1, dW2, db2, CF);
    comb_k<<<1, 256, 0, stream>>>(selfK, cplW, cplB, CB);
    final_k<<<512, 256, 0, stream>>>(Y, SB, roW, CF, CB, (float*)d_out);
}

// Round 7
// 554.344 us; speedup vs baseline: 6.0499x; 1.0561x over previous
//
#include <hip/hip_runtime.h>
#include <math.h>

// ---------------- problem constants ----------------
#define TT_   1000
#define TTOT_ 1100
#define NPAD_ 100
#define DD_   256
#define NN_   256

// workspace layout (float units)
#define X_OFF    0u           // fp32 residual 16000x256
#define XB_OFF   4096000u     // bf16 X
#define O_OFF    6144000u     // bf16 attn out
#define R_OFF    8192000u     // fp32 pre-LN
#define BIG_OFF  12288000u    // bf16 16000x1024 max (also Ybt before qkv)
#define WT_OFF   20480000u    // bf16 weights: qkv|o|w1|w2|tok = 3211264 shorts
#define PE_OFF   22085632u    // fp32 pos-enc 1000x256
#define PP_OFF   22341632u
#define PL_OFF   (PP_OFF + 32768u)
#define CF_OFF   (PL_OFF + 4096u)
#define CB_OFF   (CF_OFF + 1920u)
#define BQ_OFF   (CB_OFF + 5120u)   // scaled bqkv 4x768
#define STL_OFF  (BQ_OFF + 3072u)   // sti_lat 16x4x1000

#define SC2_ 0.25503902254649546f   // (1/sqrt(32)) * log2(e)

typedef __attribute__((ext_vector_type(8))) short s16x8;
typedef __attribute__((ext_vector_type(4))) float f32x4;
typedef __attribute__((ext_vector_type(16))) float f32x16;
typedef __attribute__((ext_vector_type(4))) unsigned u32x4;

__device__ inline short f2bf(float f) {
    unsigned u = __float_as_uint(f);
    u += 0x7fffu + ((u >> 16) & 1u);
    return (short)(u >> 16);
}
__device__ inline float exp2i(float x) {   // native 2^x
    float r; asm("v_exp_f32 %0, %1" : "=v"(r) : "v"(x)); return r;
}

// async global->LDS, 16B per lane; LDS dest linear in lane order.
__device__ inline void gl_lds16(const short* g, short* l) {
    __builtin_amdgcn_global_load_lds(
        (const __attribute__((address_space(1))) void*)g,
        (__attribute__((address_space(3))) void*)l, 16, 0, 0);
}

// ---------------- weight transpose-convert (rows < qrows scaled by qs) ----------------
__global__ __launch_bounds__(256) void wtr_k(const float* __restrict__ in,
                                             short* __restrict__ out, int K, int N,
                                             int qrows, float qs)
{
    __shared__ float t[32][33];
    const int n0 = blockIdx.x * 32, k0 = blockIdx.y * 32;
    in  += (size_t)blockIdx.z * K * N;
    out += (size_t)blockIdx.z * K * N;
    const int tx = threadIdx.x & 31, ty = threadIdx.x >> 5;
    #pragma unroll
    for (int i = 0; i < 4; ++i)
        t[ty + 8 * i][tx] = in[(size_t)(k0 + ty + 8 * i) * N + n0 + tx];
    __syncthreads();
    #pragma unroll
    for (int i = 0; i < 4; ++i) {
        const int row = n0 + ty + 8 * i;
        float f = t[tx][ty + 8 * i];
        if (row < qrows) f *= qs;
        out[(size_t)row * K + k0 + tx] = f2bf(f);
    }
}

// ---------------- Y transpose-convert: Ybt[(b*1000+t)][n] = bf16(Y[b][n][100+t]) ----------------
__global__ __launch_bounds__(256) void ytr_k(const float* __restrict__ Y,
                                             short* __restrict__ out)
{
    __shared__ float t[32][33];
    const int b = blockIdx.z;
    const int t0 = blockIdx.x * 32, n0 = blockIdx.y * 32;
    const int tx = threadIdx.x & 31, ty = threadIdx.x >> 5;
    #pragma unroll
    for (int i = 0; i < 4; ++i) {
        const int tt = t0 + tx;
        t[ty + 8 * i][tx] = (tt < TT_)
            ? Y[((size_t)(b * NN_ + n0 + ty + 8 * i)) * TTOT_ + NPAD_ + tt] : 0.f;
    }
    __syncthreads();
    #pragma unroll
    for (int i = 0; i < 4; ++i) {
        const int tt = t0 + ty + 8 * i;
        if (tt < TT_)
            out[((size_t)(b * TT_ + tt)) * NN_ + n0 + tx] = f2bf(t[tx][ty + 8 * i]);
    }
}

// ---------------- positional-encoding table ----------------
__global__ void pe_k(float* __restrict__ PE)
{
    const int t = blockIdx.x, d = threadIdx.x;
    const float div = __expf(-(float)(d & ~1) * 0.0269834190585241f); // ln(1000)/256
    const float ang = (float)t * div;
    PE[t * 256 + d] = (d & 1) ? cosf(ang) : sinf(ang);
}

// ---------------- scaled bias copy (qkv: cols<256 scaled) ----------------
__global__ void bscale_k(const float* __restrict__ in, float* __restrict__ out)
{
    const int i = blockIdx.x * 256 + threadIdx.x;
    if (i < 3072) {
        const int col = i % 768;
        out[i] = in[i] * ((col < 256) ? SC2_ : 1.f);
    }
}

// ---------------- bf16 MFMA GEMM (64x128 tile, 4 waves, single-buffer) ----------------
template<int OUTBF, int ACT, int RES, int DUAL>
__global__ __launch_bounds__(256) void bgemm_k(const short* __restrict__ A,
                                               const short* __restrict__ Bt,
                                               const float* __restrict__ bias,
                                               const float* __restrict__ resid,
                                               void* __restrict__ Cout,
                                               short* __restrict__ Cb,
                                               int M, int N, int K, int nby)
{
    __shared__ short As[64 * 64];
    __shared__ short Bs[128 * 64];
    const int tid = threadIdx.x;

    const int nwg = gridDim.x;
    int gid = blockIdx.x;
    {
        const int q = nwg >> 3, r = nwg & 7;
        const int x = gid & 7, idx = gid >> 3;
        gid = (x < r ? x * (q + 1) : r * (q + 1) + (x - r) * q) + idx;
    }
    const int bx = gid / nby, by = gid - bx * nby;
    const int m0 = bx * 64, n0 = by * 128;

    const int wv = tid >> 6, lane = tid & 63;
    const int wr = wv >> 1, wc = wv & 1;
    const int l15 = lane & 15, lg = lane >> 4;

    f32x4 acc[2][4];
    #pragma unroll
    for (int i = 0; i < 2; ++i)
        #pragma unroll
        for (int j = 0; j < 4; ++j) acc[i][j] = (f32x4){0.f, 0.f, 0.f, 0.f};

    const int nt = K >> 6;
    for (int t = 0; t < nt; ++t) {
        __syncthreads();
        const int k0 = t << 6;
        #pragma unroll
        for (int i = 0; i < 2; ++i) {
            const int cid = i * 256 + tid;
            const int r = cid >> 3, c = cid & 7;
            gl_lds16(A + (size_t)(m0 + r) * K + k0 + ((c ^ (r & 7)) * 8), As + cid * 8);
        }
        #pragma unroll
        for (int i = 0; i < 4; ++i) {
            const int cid = i * 256 + tid;
            const int r = cid >> 3, c = cid & 7;
            gl_lds16(Bt + (size_t)(n0 + r) * K + k0 + ((c ^ (r & 7)) * 8), Bs + cid * 8);
        }
        __syncthreads();

        #pragma unroll
        for (int ks = 0; ks < 2; ++ks) {
            s16x8 af[2], bf[4];
            #pragma unroll
            for (int mi = 0; mi < 2; ++mi) {
                const int row = wr * 32 + mi * 16 + l15;
                const int ch = ks * 4 + lg;
                af[mi] = *(const s16x8*)(As + row * 64 + ((ch ^ (row & 7)) * 8));
            }
            #pragma unroll
            for (int ni = 0; ni < 4; ++ni) {
                const int col = wc * 64 + ni * 16 + l15;
                const int ch = ks * 4 + lg;
                bf[ni] = *(const s16x8*)(Bs + col * 64 + ((ch ^ (col & 7)) * 8));
            }
            #pragma unroll
            for (int mi = 0; mi < 2; ++mi)
                #pragma unroll
                for (int ni = 0; ni < 4; ++ni)
                    acc[mi][ni] = __builtin_amdgcn_mfma_f32_16x16x32_bf16(
                        af[mi], bf[ni], acc[mi][ni], 0, 0, 0);
        }
    }

    #pragma unroll
    for (int mi = 0; mi < 2; ++mi) {
        #pragma unroll
        for (int ni = 0; ni < 4; ++ni) {
            const int col = n0 + wc * 64 + ni * 16 + l15;
            const float bv = bias[col];
            #pragma unroll
            for (int r = 0; r < 4; ++r) {
                const int row = m0 + wr * 32 + mi * 16 + lg * 4 + r;
                float v = acc[mi][ni][r] + bv;
                if (RES == 1) v += resid[(size_t)row * N + col];
                if (RES == 2) v += resid[(size_t)(row % 1000) * N + col];
                if (ACT) v = 0.5f * v * (1.0f + erff(v * 0.70710678118654752f));
                if (OUTBF) ((short*)Cout)[(size_t)row * N + col] = f2bf(v);
                else       ((float*)Cout)[(size_t)row * N + col] = v;
                if (DUAL)  Cb[(size_t)row * N + col] = f2bf(v);
            }
        }
    }
}

// ---------------- MFMA flash attention: swapped QK^T, no-max softmax ----------------
__global__ __launch_bounds__(256) void mattn_k(const short* __restrict__ qkv,
                                               short* __restrict__ o)
{
    int wg = blockIdx.x;
    wg = (wg & 7) * 128 + (wg >> 3);
    const int qt = wg & 7, h = (wg >> 3) & 7, b = wg >> 6;

    const int tid = threadIdx.x, wv = tid >> 6, lane = tid & 63;
    const int q31 = lane & 31, hi = lane >> 5;
    __shared__ short Ks[2][64 * 40];
    __shared__ short VT[2][32 * 72];

    const int q0w = qt * 128 + wv * 32;
    int qrow = q0w + q31; if (qrow > 999) qrow = 999;
    s16x8 bq[2];
    #pragma unroll
    for (int dh = 0; dh < 2; ++dh)
        bq[dh] = *(const s16x8*)(qkv + ((size_t)(b * TT_ + qrow)) * 768 + h * 32 + dh * 16 + hi * 8);

    f32x16 oacc;
    #pragma unroll
    for (int i = 0; i < 16; ++i) oacc[i] = 0.f;
    float lrun = 0.f;

    const int sr = tid >> 2, sc = tid & 3;
    s16x8 kreg, vreg;
    auto LOADT = [&](int kt) {
        int t = kt * 64 + sr; if (t > 999) t = 999;
        const short* src = qkv + ((size_t)(b * TT_ + t)) * 768 + 256 + h * 32;
        kreg = *(const s16x8*)(src + sc * 8);
        vreg = *(const s16x8*)(src + 256 + sc * 8);
    };
    auto WRITET = [&](int buf) {
        *(s16x8*)(&Ks[buf][sr * 40 + sc * 8]) = kreg;
        #pragma unroll
        for (int j = 0; j < 8; ++j)
            VT[buf][(sc * 8 + j) * 72 + (((sr >> 3) ^ sc) * 8) + (sr & 7)] = vreg[j];
    };

    LOADT(0); WRITET(0);
    __syncthreads();
    int cur = 0;

    for (int kt = 0; kt < 16; ++kt) {
        if (kt < 15) LOADT(kt + 1);

        f32x16 st[2];
        __builtin_amdgcn_s_setprio(1);
        #pragma unroll
        for (int kb = 0; kb < 2; ++kb) {
            s16x8 kf0 = *(const s16x8*)(&Ks[cur][(kb * 32 + q31) * 40 + hi * 8]);
            s16x8 kf1 = *(const s16x8*)(&Ks[cur][(kb * 32 + q31) * 40 + 16 + hi * 8]);
            f32x16 z;
            #pragma unroll
            for (int i = 0; i < 16; ++i) z[i] = 0.f;
            z = __builtin_amdgcn_mfma_f32_32x32x16_bf16(kf0, bq[0], z, 0, 0, 0);
            z = __builtin_amdgcn_mfma_f32_32x32x16_bf16(kf1, bq[1], z, 0, 0, 0);
            st[kb] = z;
        }
        __builtin_amdgcn_s_setprio(0);

        if (kt == 15) {
            #pragma unroll
            for (int kb = 0; kb < 2; ++kb)
                #pragma unroll
                for (int r = 0; r < 16; ++r) {
                    const int kloc = kb * 32 + (r & 3) + 8 * (r >> 2) + 4 * hi;
                    if (960 + kloc >= TT_) st[kb][r] = -1e30f;
                }
        }

        float sloc = 0.f;
        #pragma unroll
        for (int kb = 0; kb < 2; ++kb)
            #pragma unroll
            for (int r = 0; r < 16; ++r) {
                const float p = exp2i(st[kb][r]);
                st[kb][r] = p; sloc += p;
            }
        sloc += __shfl_xor(sloc, 32);
        lrun += sloc;

        unsigned wk[2][4][2];
        #pragma unroll
        for (int kb = 0; kb < 2; ++kb)
            #pragma unroll
            for (int a = 0; a < 4; ++a)
                #pragma unroll
                for (int h2 = 0; h2 < 2; ++h2) {
                    unsigned rr;
                    asm("v_cvt_pk_bf16_f32 %0, %1, %2"
                        : "=v"(rr)
                        : "v"(st[kb][4 * a + 2 * h2]), "v"(st[kb][4 * a + 2 * h2 + 1]));
                    wk[kb][a][h2] = rr;
                }

        #pragma unroll
        for (int ks = 0; ks < 4; ++ks) {
            const int kb = ks >> 1, qq = ks & 1;
            unsigned W[4];
            #pragma unroll
            for (int h2 = 0; h2 < 2; ++h2) {
                const unsigned send = hi ? wk[kb][2 * qq][h2] : wk[kb][2 * qq + 1][h2];
                const unsigned recv = __shfl_xor(send, 32);
                W[h2]     = hi ? recv : wk[kb][2 * qq][h2];
                W[2 + h2] = hi ? wk[kb][2 * qq + 1][h2] : recv;
            }
            u32x4 w4 = (u32x4){W[0], W[1], W[2], W[3]};
            s16x8 pb = __builtin_bit_cast(s16x8, w4);
            s16x8 vf = *(const s16x8*)(&VT[cur][q31 * 72 + (((2 * ks + hi) ^ (q31 >> 3)) * 8)]);
            __builtin_amdgcn_s_setprio(1);
            oacc = __builtin_amdgcn_mfma_f32_32x32x16_bf16(vf, pb, oacc, 0, 0, 0);
            __builtin_amdgcn_s_setprio(0);
        }

        if (kt < 15) WRITET(cur ^ 1);
        __syncthreads();
        cur ^= 1;
    }

    const int t = q0w + q31;
    if (t < TT_) {
        const float inv = 1.f / lrun;
        short* ob = o + ((size_t)(b * TT_ + t)) * 256 + h * 32;
        #pragma unroll
        for (int a = 0; a < 4; ++a) {
            unsigned w0, w1;
            asm("v_cvt_pk_bf16_f32 %0, %1, %2"
                : "=v"(w0) : "v"(oacc[4 * a + 0] * inv), "v"(oacc[4 * a + 1] * inv));
            asm("v_cvt_pk_bf16_f32 %0, %1, %2"
                : "=v"(w1) : "v"(oacc[4 * a + 2] * inv), "v"(oacc[4 * a + 3] * inv));
            const int d0 = 8 * a + 4 * hi;
            *(unsigned*)(ob + d0) = w0;
            *(unsigned*)(ob + d0 + 2) = w1;
        }
    }
}

// ---------------- LayerNorm: 4 rows/block, 1 wave/row, float4 ----------------
__global__ __launch_bounds__(256) void ln_k(const float* __restrict__ in,
                                            const float* __restrict__ g,
                                            const float* __restrict__ b,
                                            float* __restrict__ out,
                                            short* __restrict__ outb)
{
    const int row = blockIdx.x * 4 + (threadIdx.x >> 6);
    const int lane = threadIdx.x & 63;
    const size_t base = (size_t)row * 256 + lane * 4;
    float4 v = *(const float4*)(in + base);
    float s = v.x + v.y + v.z + v.w;
    #pragma unroll
    for (int msk = 1; msk < 64; msk <<= 1) s += __shfl_xor(s, msk);
    const float mean = s * (1.f / 256.f);
    float4 d; d.x = v.x - mean; d.y = v.y - mean; d.z = v.z - mean; d.w = v.w - mean;
    float q = d.x * d.x + d.y * d.y + d.z * d.z + d.w * d.w;
    #pragma unroll
    for (int msk = 1; msk < 64; msk <<= 1) q += __shfl_xor(q, msk);
    const float rs = rsqrtf(q * (1.f / 256.f) + 1e-5f);
    const float4 g4 = *(const float4*)(g + lane * 4);
    const float4 b4 = *(const float4*)(b + lane * 4);
    float4 o4;
    o4.x = d.x * rs * g4.x + b4.x;
    o4.y = d.y * rs * g4.y + b4.y;
    o4.z = d.z * rs * g4.z + b4.z;
    o4.w = d.w * rs * g4.w + b4.w;
    *(float4*)(out + base) = o4;
    short4 s4;
    s4.x = f2bf(o4.x); s4.y = f2bf(o4.y); s4.z = f2bf(o4.z); s4.w = f2bf(o4.w);
    *(short4*)(outb + base) = s4;
}

// ---------------- mean pool ----------------
__global__ __launch_bounds__(256) void pool_part_k(const float* __restrict__ X,
                                                   float* __restrict__ partial)
{
    const int b = blockIdx.x, seg = blockIdx.y, d = threadIdx.x;
    float s = 0.f;
    const int t0 = seg * 125;
    for (int t = t0; t < t0 + 125; ++t) s += X[((size_t)b * TT_ + t) * 256 + d];
    partial[(b * 8 + seg) * 256 + d] = s;
}
__global__ __launch_bounds__(256) void pool_red_k(const float* __restrict__ partial,
                                                  float* __restrict__ pooled)
{
    const int b = blockIdx.x, d = threadIdx.x;
    float s = 0.f;
    for (int k = 0; k < 8; ++k) s += partial[(b * 8 + k) * 256 + d];
    pooled[b * 256 + d] = s * (1.f / (float)TT_);
}

// ---------------- decode head ----------------
__global__ __launch_bounds__(128) void head_k(const float* __restrict__ pooled,
                                              const float* __restrict__ toLW,
                                              const float* __restrict__ toLb,
                                              const float* __restrict__ dW1,
                                              const float* __restrict__ db1,
                                              const float* __restrict__ dW2,
                                              const float* __restrict__ db2,
                                              float* __restrict__ coeffs)
{
    const int b = blockIdx.x, j = threadIdx.x;
    __shared__ float hs[64];
    __shared__ float hid[128];
    float a = toLb[j];
    for (int d = 0; d < 256; ++d) a += pooled[b * 256 + d] * toLW[d * 128 + j];
    if (j < 64) hs[j] = a;
    __syncthreads();
    float a2 = db1[j];
    for (int z = 0; z < 64; ++z) a2 += hs[z] * dW1[z * 128 + j];
    hid[j] = fmaxf(a2, 0.f);
    __syncthreads();
    if (j < 120) {
        float a3 = db2[j];
        for (int k = 0; k < 128; ++k) a3 += hid[k] * dW2[k * 120 + j];
        coeffs[b * 120 + j] = a3;
    }
}

// ---------------- combined conv kernel ----------------
__global__ void comb_k(const float* __restrict__ selfK,
                       const float* __restrict__ cplW,
                       const float* __restrict__ cplB,
                       float* __restrict__ comb)
{
    const int n = threadIdx.x;
    for (int ti = 0; ti < 20; ++ti) {
        float s = selfK[ti * 256 + n];
        #pragma unroll
        for (int si = 0; si < 4; ++si) s += cplW[n * 4 + si] * cplB[ti * 4 + si];
        comb[n * 20 + ti] = s;
    }
}

// ---------------- sti_lat: STL[b*4+f][t] = sum_k coeffs[b,f,k]*SB[t,k] ----------------
__global__ __launch_bounds__(256) void stilat_k(const float* __restrict__ SB,
                                                const float* __restrict__ coeffs,
                                                float* __restrict__ STL)
{
    const int bf = blockIdx.x;             // 0..63
    __shared__ float c[30];
    if (threadIdx.x < 30) c[threadIdx.x] = coeffs[(bf >> 2) * 120 + (bf & 3) * 30 + threadIdx.x];
    __syncthreads();
    for (int t = threadIdx.x; t < TT_; t += 256) {
        float acc = 0.f;
        const float* sp = SB + (size_t)t * 30;
        #pragma unroll
        for (int k = 0; k < 30; ++k) acc += c[k] * sp[k];
        STL[bf * TT_ + t] = acc;
    }
}

// ---------------- final: 8 neurons x 250 t per block ----------------
__global__ __launch_bounds__(256) void final_k(const float* __restrict__ Y,
                                               const float* __restrict__ STL,
                                               const float* __restrict__ roW,
                                               const float* __restrict__ comb,
                                               float* __restrict__ out)
{
    const int bx = blockIdx.x;             // b(4b) | nc(5b) | ts(2b)
    const int ts = bx & 3, nc = (bx >> 2) & 31, b = bx >> 7;
    const int n0 = nc * 8, t0 = ts * 250;
    const int tid = threadIdx.x;
    __shared__ float rw[8][4], ck[8][20], yl[8][272];

    if (tid < 32) rw[tid >> 2][tid & 3] = roW[(n0 + (tid >> 2)) * 4 + (tid & 3)];
    if (tid >= 64 && tid < 224) {
        const int j = tid - 64;
        ck[j / 20][j % 20] = comb[(n0 + j / 20) * 20 + (j % 20)];
    }
    for (int j = tid; j < 2160; j += 256) {
        const int n = j / 270, jj = j - n * 270;
        yl[n][jj] = Y[((size_t)(b * 256 + n0 + n)) * TTOT_ + t0 + 80 + jj];
    }
    __syncthreads();

    if (tid < 250) {
        const int t = t0 + tid;
        float s4[4];
        #pragma unroll
        for (int f = 0; f < 4; ++f) s4[f] = STL[((size_t)b * 4 + f) * TT_ + t];
        #pragma unroll
        for (int n = 0; n < 8; ++n) {
            float acc = rw[n][0] * s4[0] + rw[n][1] * s4[1]
                      + rw[n][2] * s4[2] + rw[n][3] * s4[3];
            #pragma unroll
            for (int tau = 1; tau <= 20; ++tau)
                acc += ck[n][tau - 1] * yl[n][tid + 20 - tau];
            out[((size_t)(b * 256 + n0 + n)) * TT_ + t] = acc;
        }
    }
}

// ---------------- launch ----------------
extern "C" void kernel_launch(void* const* d_in, const int* in_sizes, int n_in,
                              void* d_out, int out_size, void* d_ws, size_t ws_size,
                              hipStream_t stream)
{
    const float* Y      = (const float*)d_in[0];
    const float* tokW   = (const float*)d_in[1];
    const float* tokb   = (const float*)d_in[2];
    const float* Wqkv   = (const float*)d_in[3];
    const float* bqkv   = (const float*)d_in[4];
    const float* Wo     = (const float*)d_in[5];
    const float* bo     = (const float*)d_in[6];
    const float* ln1g   = (const float*)d_in[7];
    const float* ln1b   = (const float*)d_in[8];
    const float* W1     = (const float*)d_in[9];
    const float* b1     = (const float*)d_in[10];
    const float* W2     = (const float*)d_in[11];
    const float* b2     = (const float*)d_in[12];
    const float* ln2g   = (const float*)d_in[13];
    const float* ln2b   = (const float*)d_in[14];
    const float* toLW   = (const float*)d_in[15];
    const float* toLb   = (const float*)d_in[16];
    const float* dW1    = (const float*)d_in[17];
    const float* db1    = (const float*)d_in[18];
    const float* dW2    = (const float*)d_in[19];
    const float* db2    = (const float*)d_in[20];
    const float* SB     = (const float*)d_in[21];
    const float* roW    = (const float*)d_in[22];
    const float* cplW   = (const float*)d_in[23];
    const float* cplB   = (const float*)d_in[24];
    const float* selfK  = (const float*)d_in[25];

    float* ws  = (float*)d_ws;
    float* X   = ws + X_OFF;
    short* Xb  = (short*)(ws + XB_OFF);
    short* O   = (short*)(ws + O_OFF);
    float* R   = ws + R_OFF;
    short* BIG = (short*)(ws + BIG_OFF);
    short* WT  = (short*)(ws + WT_OFF);
    float* PE  = ws + PE_OFF;
    float* PP  = ws + PP_OFF;
    float* PL  = ws + PL_OFF;
    float* CF  = ws + CF_OFF;
    float* CB  = ws + CB_OFF;
    float* BQ  = ws + BQ_OFF;
    float* STL = ws + STL_OFF;

    short* WTqkv = WT;                 // 4 x 768x256 (Q rows pre-scaled)
    short* WTo   = WT + 786432;        // 4 x 256x256
    short* WTw1  = WT + 1048576;       // 4 x 1024x256
    short* WTw2  = WT + 2097152;       // 4 x 256x1024
    short* WTtok = WT + 3145728;       // 256x256
    short* Ybt   = BIG;                // 16000x256 bf16 (freed before qkv use)

    wtr_k<<<dim3(24, 8, 4), 256, 0, stream>>>(Wqkv, WTqkv, 256, 768, 256, SC2_);
    wtr_k<<<dim3(8, 8, 4),  256, 0, stream>>>(Wo,   WTo,   256, 256, 0, 1.f);
    wtr_k<<<dim3(32, 8, 4), 256, 0, stream>>>(W1,   WTw1,  256, 1024, 0, 1.f);
    wtr_k<<<dim3(8, 32, 4), 256, 0, stream>>>(W2,   WTw2,  1024, 256, 0, 1.f);
    wtr_k<<<dim3(8, 8, 1),  256, 0, stream>>>(tokW, WTtok, 256, 256, 0, 1.f);
    bscale_k<<<12, 256, 0, stream>>>(bqkv, BQ);
    pe_k<<<1000, 256, 0, stream>>>(PE);
    ytr_k<<<dim3(32, 8, 16), 256, 0, stream>>>(Y, Ybt);

    // embed: X = Ybt @ tokW + tokb + PE  (fp32 + bf16 out)
    bgemm_k<0, 0, 2, 1><<<500, 256, 0, stream>>>(
        Ybt, WTtok, tokb, PE, X, Xb, 16000, 256, 256, 2);

    for (int l = 0; l < 4; ++l) {
        bgemm_k<1, 0, 0, 0><<<1500, 256, 0, stream>>>(
            Xb, WTqkv + (size_t)l * 196608, BQ + l * 768, nullptr, BIG, nullptr,
            16000, 768, 256, 6);
        mattn_k<<<1024, 256, 0, stream>>>(BIG, O);
        bgemm_k<0, 0, 1, 0><<<500, 256, 0, stream>>>(
            O, WTo + (size_t)l * 65536, bo + l * 256, X, R, nullptr,
            16000, 256, 256, 2);
        ln_k<<<4000, 256, 0, stream>>>(R, ln1g + l * 256, ln1b + l * 256, X, Xb);
        bgemm_k<1, 1, 0, 0><<<2000, 256, 0, stream>>>(
            Xb, WTw1 + (size_t)l * 262144, b1 + l * 1024, nullptr, BIG, nullptr,
            16000, 1024, 256, 8);
        bgemm_k<0, 0, 1, 0><<<500, 256, 0, stream>>>(
            BIG, WTw2 + (size_t)l * 262144, b2 + l * 256, X, R, nullptr,
            16000, 256, 1024, 2);
        ln_k<<<4000, 256, 0, stream>>>(R, ln2g + l * 256, ln2b + l * 256, X, Xb);
    }

    pool_part_k<<<dim3(16, 8), 256, 0, stream>>>(X, PP);
    pool_red_k<<<16, 256, 0, stream>>>(PP, PL);
    head_k<<<16, 128, 0, stream>>>(PL, toLW, toLb, dW1, db1, dW2, db2, CF);
    comb_k<<<1, 256, 0, stream>>>(selfK, cplW, cplB, CB);
    stilat_k<<<64, 256, 0, stream>>>(SB, CF, STL);
    final_k<<<2048, 256, 0, stream>>>(Y, STL, roW, CB, (float*)d_out);
}